// Round 3
// baseline (767.635 us; speedup 1.0000x reference)
//
#include <hip/hip_runtime.h>

// ---------------------------------------------------------------------------
// TfmrAttention: B=2, S=2048, E=1024, H=16, D=64
// out = [attn_out (4,194,304 f32) | attn_weights (134,217,728 f32)]
// R3: k_attn load-balance (co-resident blocks carry constant causal work).
// R4: proj 128x64 (2 blk/CU); pass-1 single-exp update; pass-2 V hoist.
// R5: nt stores on Wout/proj (L2 hygiene for K/V); cvt_pk PA pack.
// R6: (1) pass-2 K prefetch 1 tile ahead (pass 2 had ZERO lookahead — the
//     4 QK MFMAs ate a full L2 latency per tile on the critical path);
//     (2) masked-region zero-fill moved to kernel start (writes drain under
//     compute, not against kernel-end); (3) s_setprio(1) around k_attn MFMA
//     clusters (barrier-free phase-diverse waves = T5-positive regime).
// ---------------------------------------------------------------------------

typedef unsigned short u16;
typedef __attribute__((ext_vector_type(8))) short bf16x8;   // 8 bf16 = 4 VGPRs
typedef __attribute__((ext_vector_type(4))) float f32x4;
typedef __attribute__((ext_vector_type(4))) unsigned short u16x4;
typedef __attribute__((ext_vector_type(4))) unsigned int u32x4;

#define MFMA(a, b, c) __builtin_amdgcn_mfma_f32_16x16x32_bf16((a), (b), (c), 0, 0, 0)

typedef const __attribute__((address_space(1))) void* gas_t;
typedef __attribute__((address_space(3))) void* las_t;
__device__ __forceinline__ void async_copy16(const void* g, void* l) {
  __builtin_amdgcn_global_load_lds((gas_t)g, (las_t)l, 16, 0, 0);
}

__device__ __forceinline__ u16 f2bf(float f) {          // RNE fp32->bf16
  unsigned u = __builtin_bit_cast(unsigned, f);
  u += 0x7FFFu + ((u >> 16) & 1u);
  return (u16)(u >> 16);
}
__device__ __forceinline__ float E2(float x) { return __builtin_amdgcn_exp2f(x); }
__device__ __forceinline__ unsigned cvtpk_bf16(float lo, float hi) {
  unsigned r;                                           // {lo16,hi16} RNE pack
  asm("v_cvt_pk_bf16_f32 %0, %1, %2" : "=v"(r) : "v"(lo), "v"(hi));
  return r;
}

// 0.125 * log2(e): fold 1/sqrt(64) and natural->base2 exp into Q
#define QSCALE 0.18033688011112042f

// ---- cast fp32 -> bf16, 4 elems/thread ------------------------------------
__global__ __launch_bounds__(256) void k_cast(const float* __restrict__ in,
                                              u16* __restrict__ out, int n) {
  int i = (blockIdx.x * 256 + threadIdx.x) * 4;
  if (i + 3 < n) {
    float4 v = *(const float4*)(in + i);
    u16x4 o = { f2bf(v.x), f2bf(v.y), f2bf(v.z), f2bf(v.w) };
    *(u16x4*)(out + i) = o;
  }
}

// ---- transpose + cast: W[Kd][Nd] fp32 -> Wt[Nd][Kd] bf16 -------------------
__global__ __launch_bounds__(256) void k_transpose_cast(const float* __restrict__ in,
                                                        u16* __restrict__ out,
                                                        int Kd, int Nd) {
  __shared__ float tile[64][65];
  int n0 = blockIdx.x * 64, k0 = blockIdx.y * 64;
  int t = threadIdx.x, col = t & 63, r4 = t >> 6;
#pragma unroll
  for (int ph = 0; ph < 16; ++ph) {
    int row = ph * 4 + r4;
    tile[row][col] = in[(size_t)(k0 + row) * Nd + n0 + col];
  }
  __syncthreads();
#pragma unroll
  for (int ph = 0; ph < 16; ++ph) {
    int row = ph * 4 + r4;
    out[(size_t)(n0 + row) * Kd + k0 + col] = f2bf(tile[col][row]);
  }
}

// ---- transpose bf16: V[bh][2048][64] -> Vt[bh][64][2048] -------------------
__global__ __launch_bounds__(256) void k_transpose_v(const u16* __restrict__ V,
                                                     u16* __restrict__ Vt) {
  __shared__ u16 tile[64][65];
  int bh = blockIdx.y, s0 = blockIdx.x * 64;
  int t = threadIdx.x, col = t & 63, r4 = t >> 6;
#pragma unroll
  for (int ph = 0; ph < 16; ++ph) {
    int row = ph * 4 + r4;
    tile[row][col] = V[((size_t)bh * 2048 + s0 + row) * 64 + col];
  }
  __syncthreads();
#pragma unroll
  for (int ph = 0; ph < 16; ++ph) {
    int row = ph * 4 + r4;
    Vt[((size_t)bh * 64 + row) * 2048 + s0 + col] = tile[col][row];
  }
}

// ---- m97-style GEMM core macro: 128x128 tile, BK=32, global_load_lds -------
#define GEMM_PROLOG()                                                          \
  __shared__ u16 As[128 * 32];                                                 \
  __shared__ u16 Bs[128 * 32];                                                 \
  int t = threadIdx.x;                                                         \
  int wave = t >> 6, lane = t & 63, quad = lane >> 4, l16 = lane & 15;         \
  int wm = wave >> 1, wn = wave & 1;                                           \
  int m0 = blockIdx.y * 128, n0 = blockIdx.x * 128;                            \
  int f1 = wave * 64 + lane, f2 = f1 + 256;                                    \
  const u16* gA1 = A + (size_t)(m0 + (f1 >> 2)) * 1024 + (f1 & 3) * 8;         \
  const u16* gA2 = A + (size_t)(m0 + (f2 >> 2)) * 1024 + (f2 & 3) * 8;         \
  const u16* gB1 = Bt + (size_t)(n0 + (f1 >> 2)) * 1024 + (f1 & 3) * 8;        \
  const u16* gB2 = Bt + (size_t)(n0 + (f2 >> 2)) * 1024 + (f2 & 3) * 8;        \
  u16* lA1 = As + wave * 512;                                                  \
  u16* lA2 = As + 2048 + wave * 512;                                           \
  u16* lB1 = Bs + wave * 512;                                                  \
  u16* lB2 = Bs + 2048 + wave * 512;                                           \
  f32x4 acc[4][4];                                                             \
  for (int i = 0; i < 4; ++i)                                                  \
    for (int j = 0; j < 4; ++j) acc[i][j] = (f32x4){0.f, 0.f, 0.f, 0.f};       \
  for (int k0 = 0; k0 < 1024; k0 += 32) {                                      \
    async_copy16(gA1 + k0, lA1);                                               \
    async_copy16(gA2 + k0, lA2);                                               \
    async_copy16(gB1 + k0, lB1);                                               \
    async_copy16(gB2 + k0, lB2);                                               \
    __syncthreads();                                                           \
    bf16x8 fa[4], fb[4];                                                       \
    _Pragma("unroll") for (int i = 0; i < 4; ++i)                              \
        fa[i] = *(const bf16x8*)(As + (wm * 64 + i * 16 + l16) * 32 + quad * 8);\
    _Pragma("unroll") for (int j = 0; j < 4; ++j)                              \
        fb[j] = *(const bf16x8*)(Bs + (wn * 64 + j * 16 + l16) * 32 + quad * 8);\
    _Pragma("unroll") for (int i = 0; i < 4; ++i)                              \
      _Pragma("unroll") for (int j = 0; j < 4; ++j)                            \
          acc[i][j] = MFMA(fa[i], fb[j], acc[i][j]);                           \
    __syncthreads();                                                           \
  }

// GEMM1: hs[4096][1024] @ W[1024][3072] (+b) -> Q,K,V bf16 [b,h,s,d]
__global__ __launch_bounds__(256) void k_gemm_qkv(const u16* __restrict__ A,
                                                  const u16* __restrict__ Bt,
                                                  const float* __restrict__ bias,
                                                  u16* __restrict__ Q,
                                                  u16* __restrict__ Kp,
                                                  u16* __restrict__ V) {
  GEMM_PROLOG()
#pragma unroll
  for (int j = 0; j < 4; ++j) {
    int n = n0 + wn * 64 + j * 16 + l16;
    float bv = bias[n];
    int which = n >> 10, e = n & 1023, h = e >> 6, d = e & 63;
#pragma unroll
    for (int i = 0; i < 4; ++i)
#pragma unroll
      for (int r = 0; r < 4; ++r) {
        int m = m0 + wm * 64 + i * 16 + quad * 4 + r;
        int b = m >> 11, s = m & 2047;
        float v = acc[i][j][r] + bv;
        size_t off = ((size_t)((b * 16 + h) * 2048 + s)) * 64 + d;
        if (which == 0)      Q[off]  = f2bf(v * QSCALE);
        else if (which == 1) Kp[off] = f2bf(v);
        else                 V[off]  = f2bf(v);
      }
  }
}

// GEMM2: ctx[4096][1024] @ Wp[1024][1024] (+b) -> out fp32
// 128(M)x64(N) tile -> 512 blocks = 2 blocks/CU; nt stores (never re-read).
__global__ __launch_bounds__(256) void k_gemm_proj(const u16* __restrict__ A,
                                                   const u16* __restrict__ Bt,
                                                   const float* __restrict__ bias,
                                                   float* __restrict__ out) {
  __shared__ u16 As[128 * 32];
  __shared__ u16 Bs[64 * 32];
  int t = threadIdx.x;
  int wave = t >> 6, lane = t & 63, quad = lane >> 4, l16 = lane & 15;
  int wm = wave >> 1, wn = wave & 1;
  int m0 = blockIdx.y * 128, n0 = blockIdx.x * 64;
  int f1 = wave * 64 + lane, f2 = f1 + 256;
  const u16* gA1 = A + (size_t)(m0 + (f1 >> 2)) * 1024 + (f1 & 3) * 8;
  const u16* gA2 = A + (size_t)(m0 + (f2 >> 2)) * 1024 + (f2 & 3) * 8;
  const u16* gB1 = Bt + (size_t)(n0 + (f1 >> 2)) * 1024 + (f1 & 3) * 8;
  u16* lA1 = As + wave * 512;
  u16* lA2 = As + 2048 + wave * 512;
  u16* lB1 = Bs + wave * 512;
  f32x4 acc[4][2];
  for (int i = 0; i < 4; ++i)
    for (int j = 0; j < 2; ++j) acc[i][j] = (f32x4){0.f, 0.f, 0.f, 0.f};
  for (int k0 = 0; k0 < 1024; k0 += 32) {
    async_copy16(gA1 + k0, lA1);
    async_copy16(gA2 + k0, lA2);
    async_copy16(gB1 + k0, lB1);
    __syncthreads();
    bf16x8 fa[4], fb[2];
#pragma unroll
    for (int i = 0; i < 4; ++i)
      fa[i] = *(const bf16x8*)(As + (wm * 64 + i * 16 + l16) * 32 + quad * 8);
#pragma unroll
    for (int j = 0; j < 2; ++j)
      fb[j] = *(const bf16x8*)(Bs + (wn * 32 + j * 16 + l16) * 32 + quad * 8);
#pragma unroll
    for (int i = 0; i < 4; ++i)
#pragma unroll
      for (int j = 0; j < 2; ++j) acc[i][j] = MFMA(fa[i], fb[j], acc[i][j]);
    __syncthreads();
  }
#pragma unroll
  for (int j = 0; j < 2; ++j) {
    int n = n0 + wn * 32 + j * 16 + l16;
    float bv = bias[n];
#pragma unroll
    for (int i = 0; i < 4; ++i)
#pragma unroll
      for (int r = 0; r < 4; ++r) {
        int m = m0 + wm * 64 + i * 16 + quad * 4 + r;
        __builtin_nontemporal_store(acc[i][j][r] + bv, &out[(size_t)m * 1024 + n]);
      }
  }
}

// ---- fused causal attention ------------------------------------------------
// Grid: 1024 1-D blocks. bh = id&31, i = id>>5 -> (j = i&7, s = i>>3);
// q-tile qt = {j, 15-j, 16+j, 31-j}[s]. Co-resident blocks on a CU are ids
// ≡ c (mod 256) => same j, all four s => Σqt = 62 = constant per-CU work,
// and same bh => shared K/V in L1/L2.
__global__ __launch_bounds__(256, 4) void k_attn(const u16* __restrict__ Q,
                                                 const u16* __restrict__ Kp,
                                                 const u16* __restrict__ Vt,
                                                 u16* __restrict__ ctx,
                                                 float* __restrict__ Wout) {
  __shared__ float Pf[4][16 * 36];                    // fp32 P staging (+pad)
  int t = threadIdx.x;
  int w = t >> 6, lane = t & 63, quad = lane >> 4, l16 = lane & 15;
  int id = blockIdx.x;
  int bh = id & 31;
  int ii = id >> 5, jj = ii & 7, ss = ii >> 3;
  int qt = (ss == 0) ? jj : (ss == 1) ? 15 - jj : (ss == 2) ? 16 + jj : 31 - jj;
  int q0 = qt * 64 + w * 16;

  const u16* qrow = Q + ((size_t)bh * 2048 + q0 + l16) * 64 + quad * 8;
  bf16x8 aq0 = *(const bf16x8*)(qrow);
  bf16x8 aq1 = *(const bf16x8*)(qrow + 32);

  const u16* kbase = Kp + (size_t)bh * 2048 * 64;
  int qmax = q0 + 15;
  float* wrow = Wout + (size_t)bh * 2048 * 2048;
  int na = qmax / 32 + 1;                             // active 32-col tiles

  // R6: zero-fill the masked remainder [na*32, 2048) FIRST — the nt stores
  // drain under pass-1/2 compute instead of serializing at kernel end.
  {
    int zstart = na * 32;
    f32x4 z = {0.f, 0.f, 0.f, 0.f};
    for (int r = 0; r < 16; ++r) {
      float* rb = wrow + (size_t)(q0 + r) * 2048;
      for (int c = zstart + (lane << 2); c < 2048; c += 256)
        __builtin_nontemporal_store(z, (f32x4*)(rb + c));
    }
  }

  // ---- pass 1: dual-chain online softmax over 32-col tiles, K prefetch ----
  // single-exp update: t = exp2(-|d|), d=v-m:  d>0 ? l=fma(l,t,1),m=v : l+=t.
  // Masked lanes (v=m=-1e30 -> d=0 -> l+=1) keep m=-1e30, die at lane-merge.
  float m0[4], l0[4], m1[4], l1[4];
#pragma unroll
  for (int r = 0; r < 4; ++r) { m0[r] = m1[r] = -1e30f; l0[r] = l1[r] = 0.f; }
  int nt = (q0 + 47) >> 5;                            // 32-col tiles over [0, q0+16)

  const u16* kr0 = kbase + (size_t)l16 * 64 + quad * 8;
  bf16x8 nb00 = *(const bf16x8*)(kr0);
  bf16x8 nb01 = *(const bf16x8*)(kr0 + 32);
  bf16x8 nb10 = *(const bf16x8*)(kr0 + 1024);
  bf16x8 nb11 = *(const bf16x8*)(kr0 + 1024 + 32);
  for (int kt = 0; kt < nt; ++kt) {
    bf16x8 b00 = nb00, b01 = nb01, b10 = nb10, b11 = nb11;
    if (kt + 1 < nt) {
      const u16* kn = kbase + (size_t)((kt + 1) * 32 + l16) * 64 + quad * 8;
      nb00 = *(const bf16x8*)(kn);
      nb01 = *(const bf16x8*)(kn + 32);
      nb10 = *(const bf16x8*)(kn + 1024);
      nb11 = *(const bf16x8*)(kn + 1024 + 32);
    }
    f32x4 c0 = {0.f, 0.f, 0.f, 0.f}, c1 = c0;
    __builtin_amdgcn_s_setprio(1);
    c0 = MFMA(aq0, b00, c0);
    c0 = MFMA(aq1, b01, c0);
    c1 = MFMA(aq0, b10, c1);
    c1 = MFMA(aq1, b11, c1);
    __builtin_amdgcn_s_setprio(0);
    int col0 = kt * 32 + l16, col1 = col0 + 16;
#pragma unroll
    for (int r = 0; r < 4; ++r) {
      int q = q0 + quad * 4 + r;
      float v0 = (col0 <= q) ? c0[r] : -1e30f;        // chain 0
      float d0 = v0 - m0[r];
      float t0 = E2(-__builtin_fabsf(d0));
      bool g0 = d0 > 0.f;
      l0[r] = g0 ? __builtin_fmaf(l0[r], t0, 1.f) : (l0[r] + t0);
      m0[r] = g0 ? v0 : m0[r];
      float v1 = (col1 <= q) ? c1[r] : -1e30f;        // chain 1 (independent)
      float d1 = v1 - m1[r];
      float t1 = E2(-__builtin_fabsf(d1));
      bool g1 = d1 > 0.f;
      l1[r] = g1 ? __builtin_fmaf(l1[r], t1, 1.f) : (l1[r] + t1);
      m1[r] = g1 ? v1 : m1[r];
    }
  }
  float m[4], l[4];
#pragma unroll
  for (int r = 0; r < 4; ++r) {                       // merge the two chains
    float nm = fmaxf(m0[r], m1[r]);
    l[r] = l0[r] * E2(m0[r] - nm) + l1[r] * E2(m1[r] - nm);
    m[r] = nm;
  }
#pragma unroll
  for (int r = 0; r < 4; ++r) {                       // width-16 lane merge
#pragma unroll
    for (int off = 1; off < 16; off <<= 1) {
      float om = __shfl_xor(m[r], off, 16);
      float ol = __shfl_xor(l[r], off, 16);
      float nm = fmaxf(m[r], om);
      l[r] = l[r] * E2(m[r] - nm) + ol * E2(om - nm);
      m[r] = nm;
    }
  }
  float rl[4];
#pragma unroll
  for (int r = 0; r < 4; ++r) rl[r] = 1.f / l[r];

  // ---- pass 2: K double-buffered in registers (R6) ------------------------
  f32x4 oacc[4];
#pragma unroll
  for (int s4 = 0; s4 < 4; ++s4) oacc[s4] = (f32x4){0.f, 0.f, 0.f, 0.f};
  float* pf = &Pf[w][0];
  const u16* vtb = Vt + (size_t)bh * 64 * 2048;
  int srow = lane >> 3, scol = (lane & 7) << 2;       // coalesced store map

  const u16* krp = kbase + (size_t)l16 * 64 + quad * 8;
  bf16x8 kb00 = *(const bf16x8*)(krp);
  bf16x8 kb01 = *(const bf16x8*)(krp + 32);
  bf16x8 kb10 = *(const bf16x8*)(krp + 1024);
  bf16x8 kb11 = *(const bf16x8*)(krp + 1024 + 32);
  for (int kt2 = 0; kt2 < na; ++kt2) {
    int k0 = kt2 * 32;
    // V loads for the current tile — latency hides under QK^T + softmax.
    bf16x8 bv[4];
#pragma unroll
    for (int s4 = 0; s4 < 4; ++s4)
      bv[s4] = *(const bf16x8*)(vtb + (size_t)(s4 * 16 + l16) * 2048 + k0 + quad * 8);
    f32x4 cc[2] = {{0.f,0.f,0.f,0.f}, {0.f,0.f,0.f,0.f}};
    __builtin_amdgcn_s_setprio(1);
    cc[0] = MFMA(aq0, kb00, cc[0]);
    cc[0] = MFMA(aq1, kb01, cc[0]);
    cc[1] = MFMA(aq0, kb10, cc[1]);
    cc[1] = MFMA(aq1, kb11, cc[1]);
    __builtin_amdgcn_s_setprio(0);
    // prefetch K(t+1): completes under softmax + LDS round-trip + PV.
    if (kt2 + 1 < na) {
      const u16* kn = kbase + (size_t)(k0 + 32 + l16) * 64 + quad * 8;
      kb00 = *(const bf16x8*)(kn);
      kb01 = *(const bf16x8*)(kn + 32);
      kb10 = *(const bf16x8*)(kn + 1024);
      kb11 = *(const bf16x8*)(kn + 1024 + 32);
    }
#pragma unroll
    for (int sub = 0; sub < 2; ++sub) {
      int col = k0 + sub * 16 + l16;
#pragma unroll
      for (int r = 0; r < 4; ++r) {
        int q = q0 + quad * 4 + r;
        float p = (col <= q) ? E2(cc[sub][r] - m[r]) * rl[r] : 0.f;
        pf[(quad * 4 + r) * 36 + sub * 16 + l16] = p;
      }
    }
    // coalesced fp32 nt store: 2 float4/lane, 8 rows x 128B per instr
    f32x4 v0 = *(const f32x4*)(pf + srow * 36 + scol);
    f32x4 v1 = *(const f32x4*)(pf + (srow + 8) * 36 + scol);
    __builtin_nontemporal_store(v0, (f32x4*)(wrow + (size_t)(q0 + srow) * 2048 + k0 + scol));
    __builtin_nontemporal_store(v1, (f32x4*)(wrow + (size_t)(q0 + srow + 8) * 2048 + k0 + scol));
    // PA fragment from fp32 staging; packed RNE cvt (4 instr for 8 elems)
    f32x4 pa0 = *(const f32x4*)(pf + l16 * 36 + quad * 8);
    f32x4 pa1 = *(const f32x4*)(pf + l16 * 36 + quad * 8 + 4);
    u32x4 pk;
    pk[0] = cvtpk_bf16(pa0[0], pa0[1]);
    pk[1] = cvtpk_bf16(pa0[2], pa0[3]);
    pk[2] = cvtpk_bf16(pa1[0], pa1[1]);
    pk[3] = cvtpk_bf16(pa1[2], pa1[3]);
    bf16x8 pa = __builtin_bit_cast(bf16x8, pk);
    __builtin_amdgcn_s_setprio(1);
#pragma unroll
    for (int s4 = 0; s4 < 4; ++s4) {
      oacc[s4] = MFMA(pa, bv[s4], oacc[s4]);
    }
    __builtin_amdgcn_s_setprio(0);
  }
  // ctx[b][s][h*64+d]
  int b = bh >> 4, h = bh & 15;
#pragma unroll
  for (int s4 = 0; s4 < 4; ++s4)
#pragma unroll
    for (int r = 0; r < 4; ++r) {
      int q = q0 + quad * 4 + r;
      int d = s4 * 16 + l16;
      ctx[((size_t)(b * 2048 + q)) * 1024 + h * 64 + d] = f2bf(oacc[s4][r]);
    }
}

// ---------------------------------------------------------------------------
extern "C" void kernel_launch(void* const* d_in, const int* in_sizes, int n_in,
                              void* d_out, int out_size, void* d_ws, size_t ws_size,
                              hipStream_t stream) {
  const float* hs     = (const float*)d_in[0];
  const float* w_attn = (const float*)d_in[1];
  const float* b_attn = (const float*)d_in[2];
  const float* w_proj = (const float*)d_in[3];
  const float* b_proj = (const float*)d_in[4];

  char*  outc  = (char*)d_out;
  float* out_f = (float*)d_out;
  float* Wout  = out_f + 4194304;                 // weights region (512 MB)

  // scratch carved out of d_out (dead/alive windows don't overlap):
  u16* qbuf = (u16*)outc;                         // attn_out region: Q (8 MB)
  u16* kbuf = (u16*)(outc + 8388608);             //                  K (8 MB)
  u16* hsb  = (u16*)(outc + 530579456);           // weights tail: hs bf16 (8 MB)
  u16* wtA  = (u16*)(outc + 538968064);           //               w_attn^T (6 MB)
  u16* vbuf = (u16*)(outc + 545259520);           //               V (8 MB)

  char* ws  = (char*)d_ws;                        // 18 MB of d_ws used
  u16*  vt  = (u16*)ws;                           // V^T (8 MB)
  u16*  ctx = (u16*)(ws + 8388608);               // pre-proj context (8 MB)
  u16*  wtP = (u16*)(ws + 16777216);              // w_proj^T (2 MB)

  k_cast<<<4096, 256, 0, stream>>>(hs, hsb, 4194304);
  k_transpose_cast<<<dim3(48, 16), 256, 0, stream>>>(w_attn, wtA, 1024, 3072);
  k_transpose_cast<<<dim3(16, 16), 256, 0, stream>>>(w_proj, wtP, 1024, 1024);
  k_gemm_qkv<<<dim3(24, 32), 256, 0, stream>>>(hsb, wtA, b_attn, qbuf, kbuf, vbuf);
  k_transpose_v<<<dim3(32, 32), 256, 0, stream>>>(vbuf, vt);
  k_attn<<<1024, 256, 0, stream>>>(qbuf, kbuf, vt, ctx, Wout);
  k_gemm_proj<<<dim3(16, 32), 256, 0, stream>>>(ctx, wtP, b_proj, out_f);
}

// Round 4
// 728.507 us; speedup vs baseline: 1.0537x; 1.0537x over previous
//
#include <hip/hip_runtime.h>

// ---------------------------------------------------------------------------
// TfmrAttention: B=2, S=2048, E=1024, H=16, D=64
// out = [attn_out (4,194,304 f32) | attn_weights (134,217,728 f32)]
// R3: k_attn load-balance (co-resident blocks carry constant causal work).
// R4: proj 128x64 (2 blk/CU); pass-1 single-exp update; pass-2 V hoist.
// R5: nt stores on Wout/proj (L2 hygiene for K/V); cvt_pk PA pack.  [732.6us]
// R6: REGRESSED (+35us) — bundled pass-2 K reg-dbuf (+16 VGPR under the
//     128-VGPR launch_bounds cap -> likely spills), zero-fill-at-start,
//     setprio. All three reverted here.
// R7: k_attn = exact R5. New: XCD-aware block swizzle on both GEMMs
//     (row-chunked, bijective since nwg%8==0) — each XCD owns 4 contiguous
//     m-rows x all n-tiles, so the A-panel chunk stays L2-resident and A's
//     ~192 MB of L3 re-reads collapse to ~8 MB.
// ---------------------------------------------------------------------------

typedef unsigned short u16;
typedef __attribute__((ext_vector_type(8))) short bf16x8;   // 8 bf16 = 4 VGPRs
typedef __attribute__((ext_vector_type(4))) float f32x4;
typedef __attribute__((ext_vector_type(4))) unsigned short u16x4;
typedef __attribute__((ext_vector_type(4))) unsigned int u32x4;

#define MFMA(a, b, c) __builtin_amdgcn_mfma_f32_16x16x32_bf16((a), (b), (c), 0, 0, 0)

typedef const __attribute__((address_space(1))) void* gas_t;
typedef __attribute__((address_space(3))) void* las_t;
__device__ __forceinline__ void async_copy16(const void* g, void* l) {
  __builtin_amdgcn_global_load_lds((gas_t)g, (las_t)l, 16, 0, 0);
}

__device__ __forceinline__ u16 f2bf(float f) {          // RNE fp32->bf16
  unsigned u = __builtin_bit_cast(unsigned, f);
  u += 0x7FFFu + ((u >> 16) & 1u);
  return (u16)(u >> 16);
}
__device__ __forceinline__ float E2(float x) { return __builtin_amdgcn_exp2f(x); }
__device__ __forceinline__ unsigned cvtpk_bf16(float lo, float hi) {
  unsigned r;                                           // {lo16,hi16} RNE pack
  asm("v_cvt_pk_bf16_f32 %0, %1, %2" : "=v"(r) : "v"(lo), "v"(hi));
  return r;
}

// 0.125 * log2(e): fold 1/sqrt(64) and natural->base2 exp into Q
#define QSCALE 0.18033688011112042f

// ---- cast fp32 -> bf16, 4 elems/thread ------------------------------------
__global__ __launch_bounds__(256) void k_cast(const float* __restrict__ in,
                                              u16* __restrict__ out, int n) {
  int i = (blockIdx.x * 256 + threadIdx.x) * 4;
  if (i + 3 < n) {
    float4 v = *(const float4*)(in + i);
    u16x4 o = { f2bf(v.x), f2bf(v.y), f2bf(v.z), f2bf(v.w) };
    *(u16x4*)(out + i) = o;
  }
}

// ---- transpose + cast: W[Kd][Nd] fp32 -> Wt[Nd][Kd] bf16 -------------------
__global__ __launch_bounds__(256) void k_transpose_cast(const float* __restrict__ in,
                                                        u16* __restrict__ out,
                                                        int Kd, int Nd) {
  __shared__ float tile[64][65];
  int n0 = blockIdx.x * 64, k0 = blockIdx.y * 64;
  int t = threadIdx.x, col = t & 63, r4 = t >> 6;
#pragma unroll
  for (int ph = 0; ph < 16; ++ph) {
    int row = ph * 4 + r4;
    tile[row][col] = in[(size_t)(k0 + row) * Nd + n0 + col];
  }
  __syncthreads();
#pragma unroll
  for (int ph = 0; ph < 16; ++ph) {
    int row = ph * 4 + r4;
    out[(size_t)(n0 + row) * Kd + k0 + col] = f2bf(tile[col][row]);
  }
}

// ---- transpose bf16: V[bh][2048][64] -> Vt[bh][64][2048] -------------------
__global__ __launch_bounds__(256) void k_transpose_v(const u16* __restrict__ V,
                                                     u16* __restrict__ Vt) {
  __shared__ u16 tile[64][65];
  int bh = blockIdx.y, s0 = blockIdx.x * 64;
  int t = threadIdx.x, col = t & 63, r4 = t >> 6;
#pragma unroll
  for (int ph = 0; ph < 16; ++ph) {
    int row = ph * 4 + r4;
    tile[row][col] = V[((size_t)bh * 2048 + s0 + row) * 64 + col];
  }
  __syncthreads();
#pragma unroll
  for (int ph = 0; ph < 16; ++ph) {
    int row = ph * 4 + r4;
    Vt[((size_t)bh * 64 + row) * 2048 + s0 + col] = tile[col][row];
  }
}

// ---- m97-style GEMM core macro: 128x128 tile, BK=32, global_load_lds -------
// m0/n0 must be computed by the caller (allows XCD-aware swizzle).
#define GEMM_BODY()                                                            \
  __shared__ u16 As[128 * 32];                                                 \
  __shared__ u16 Bs[128 * 32];                                                 \
  int t = threadIdx.x;                                                         \
  int wave = t >> 6, lane = t & 63, quad = lane >> 4, l16 = lane & 15;         \
  int wm = wave >> 1, wn = wave & 1;                                           \
  int f1 = wave * 64 + lane, f2 = f1 + 256;                                    \
  const u16* gA1 = A + (size_t)(m0 + (f1 >> 2)) * 1024 + (f1 & 3) * 8;         \
  const u16* gA2 = A + (size_t)(m0 + (f2 >> 2)) * 1024 + (f2 & 3) * 8;         \
  const u16* gB1 = Bt + (size_t)(n0 + (f1 >> 2)) * 1024 + (f1 & 3) * 8;        \
  const u16* gB2 = Bt + (size_t)(n0 + (f2 >> 2)) * 1024 + (f2 & 3) * 8;        \
  u16* lA1 = As + wave * 512;                                                  \
  u16* lA2 = As + 2048 + wave * 512;                                           \
  u16* lB1 = Bs + wave * 512;                                                  \
  u16* lB2 = Bs + 2048 + wave * 512;                                           \
  f32x4 acc[4][4];                                                             \
  for (int i = 0; i < 4; ++i)                                                  \
    for (int j = 0; j < 4; ++j) acc[i][j] = (f32x4){0.f, 0.f, 0.f, 0.f};       \
  for (int k0 = 0; k0 < 1024; k0 += 32) {                                      \
    async_copy16(gA1 + k0, lA1);                                               \
    async_copy16(gA2 + k0, lA2);                                               \
    async_copy16(gB1 + k0, lB1);                                               \
    async_copy16(gB2 + k0, lB2);                                               \
    __syncthreads();                                                           \
    bf16x8 fa[4], fb[4];                                                       \
    _Pragma("unroll") for (int i = 0; i < 4; ++i)                              \
        fa[i] = *(const bf16x8*)(As + (wm * 64 + i * 16 + l16) * 32 + quad * 8);\
    _Pragma("unroll") for (int j = 0; j < 4; ++j)                              \
        fb[j] = *(const bf16x8*)(Bs + (wn * 64 + j * 16 + l16) * 32 + quad * 8);\
    _Pragma("unroll") for (int i = 0; i < 4; ++i)                              \
      _Pragma("unroll") for (int j = 0; j < 4; ++j)                            \
          acc[i][j] = MFMA(fa[i], fb[j], acc[i][j]);                           \
    __syncthreads();                                                           \
  }

// GEMM1: hs[4096][1024] @ W[1024][3072] (+b) -> Q,K,V bf16 [b,h,s,d]
// R7: XCD swizzle — lid%8 selects XCD (round-robin dispatch), so wgid gives
// each XCD a contiguous chunk of 96 tiles = 4 m-rows x 24 n-tiles; the 1MB
// A-chunk stays L2-resident while n walks fastest.
__global__ __launch_bounds__(256) void k_gemm_qkv(const u16* __restrict__ A,
                                                  const u16* __restrict__ Bt,
                                                  const float* __restrict__ bias,
                                                  u16* __restrict__ Q,
                                                  u16* __restrict__ Kp,
                                                  u16* __restrict__ V) {
  int lid = blockIdx.y * 24 + blockIdx.x;             // 768 = 8 * 96
  int wg = (lid & 7) * 96 + (lid >> 3);
  int m0 = (wg / 24) * 128, n0 = (wg % 24) * 128;
  GEMM_BODY()
#pragma unroll
  for (int j = 0; j < 4; ++j) {
    int n = n0 + wn * 64 + j * 16 + l16;
    float bv = bias[n];
    int which = n >> 10, e = n & 1023, h = e >> 6, d = e & 63;
#pragma unroll
    for (int i = 0; i < 4; ++i)
#pragma unroll
      for (int r = 0; r < 4; ++r) {
        int m = m0 + wm * 64 + i * 16 + quad * 4 + r;
        int b = m >> 11, s = m & 2047;
        float v = acc[i][j][r] + bv;
        size_t off = ((size_t)((b * 16 + h) * 2048 + s)) * 64 + d;
        if (which == 0)      Q[off]  = f2bf(v * QSCALE);
        else if (which == 1) Kp[off] = f2bf(v);
        else                 V[off]  = f2bf(v);
      }
  }
}

// GEMM2: ctx[4096][1024] @ Wp[1024][1024] (+b) -> out fp32
// 128(M)x64(N) tile -> 512 blocks = 2 blocks/CU; nt stores (never re-read).
// R7: XCD swizzle (512 = 8 * 64): each XCD owns 4 m-rows x 16 n-tiles.
__global__ __launch_bounds__(256) void k_gemm_proj(const u16* __restrict__ A,
                                                   const u16* __restrict__ Bt,
                                                   const float* __restrict__ bias,
                                                   float* __restrict__ out) {
  __shared__ u16 As[128 * 32];
  __shared__ u16 Bs[64 * 32];
  int t = threadIdx.x;
  int wave = t >> 6, lane = t & 63, quad = lane >> 4, l16 = lane & 15;
  int wm = wave >> 1, wn = wave & 1;
  int lid = blockIdx.y * 16 + blockIdx.x;             // 512 = 8 * 64
  int wg = (lid & 7) * 64 + (lid >> 3);
  int m0 = (wg >> 4) * 128, n0 = (wg & 15) * 64;
  int f1 = wave * 64 + lane, f2 = f1 + 256;
  const u16* gA1 = A + (size_t)(m0 + (f1 >> 2)) * 1024 + (f1 & 3) * 8;
  const u16* gA2 = A + (size_t)(m0 + (f2 >> 2)) * 1024 + (f2 & 3) * 8;
  const u16* gB1 = Bt + (size_t)(n0 + (f1 >> 2)) * 1024 + (f1 & 3) * 8;
  u16* lA1 = As + wave * 512;
  u16* lA2 = As + 2048 + wave * 512;
  u16* lB1 = Bs + wave * 512;
  f32x4 acc[4][2];
  for (int i = 0; i < 4; ++i)
    for (int j = 0; j < 2; ++j) acc[i][j] = (f32x4){0.f, 0.f, 0.f, 0.f};
  for (int k0 = 0; k0 < 1024; k0 += 32) {
    async_copy16(gA1 + k0, lA1);
    async_copy16(gA2 + k0, lA2);
    async_copy16(gB1 + k0, lB1);
    __syncthreads();
    bf16x8 fa[4], fb[2];
#pragma unroll
    for (int i = 0; i < 4; ++i)
      fa[i] = *(const bf16x8*)(As + (wm * 64 + i * 16 + l16) * 32 + quad * 8);
#pragma unroll
    for (int j = 0; j < 2; ++j)
      fb[j] = *(const bf16x8*)(Bs + (wn * 32 + j * 16 + l16) * 32 + quad * 8);
#pragma unroll
    for (int i = 0; i < 4; ++i)
#pragma unroll
      for (int j = 0; j < 2; ++j) acc[i][j] = MFMA(fa[i], fb[j], acc[i][j]);
    __syncthreads();
  }
#pragma unroll
  for (int j = 0; j < 2; ++j) {
    int n = n0 + wn * 32 + j * 16 + l16;
    float bv = bias[n];
#pragma unroll
    for (int i = 0; i < 4; ++i)
#pragma unroll
      for (int r = 0; r < 4; ++r) {
        int m = m0 + wm * 64 + i * 16 + quad * 4 + r;
        __builtin_nontemporal_store(acc[i][j][r] + bv, &out[(size_t)m * 1024 + n]);
      }
  }
}

// ---- fused causal attention (exact R5 version, 732.6us anchor) -------------
// Grid: 1024 1-D blocks. bh = id&31, i = id>>5 -> (j = i&7, s = i>>3);
// q-tile qt = {j, 15-j, 16+j, 31-j}[s]. Co-resident blocks on a CU are ids
// ≡ c (mod 256) => same j, all four s => Σqt = 62 = constant per-CU work,
// and same bh => shared K/V in L1/L2.
__global__ __launch_bounds__(256, 4) void k_attn(const u16* __restrict__ Q,
                                                 const u16* __restrict__ Kp,
                                                 const u16* __restrict__ Vt,
                                                 u16* __restrict__ ctx,
                                                 float* __restrict__ Wout) {
  __shared__ float Pf[4][16 * 36];                    // fp32 P staging (+pad)
  int t = threadIdx.x;
  int w = t >> 6, lane = t & 63, quad = lane >> 4, l16 = lane & 15;
  int id = blockIdx.x;
  int bh = id & 31;
  int ii = id >> 5, jj = ii & 7, ss = ii >> 3;
  int qt = (ss == 0) ? jj : (ss == 1) ? 15 - jj : (ss == 2) ? 16 + jj : 31 - jj;
  int q0 = qt * 64 + w * 16;

  const u16* qrow = Q + ((size_t)bh * 2048 + q0 + l16) * 64 + quad * 8;
  bf16x8 aq0 = *(const bf16x8*)(qrow);
  bf16x8 aq1 = *(const bf16x8*)(qrow + 32);

  const u16* kbase = Kp + (size_t)bh * 2048 * 64;
  int qmax = q0 + 15;

  // ---- pass 1: dual-chain online softmax over 32-col tiles, K prefetch ----
  // single-exp update: t = exp2(-|d|), d=v-m:  d>0 ? l=fma(l,t,1),m=v : l+=t.
  // Masked lanes (v=m=-1e30 -> d=0 -> l+=1) keep m=-1e30, die at lane-merge.
  float m0[4], l0[4], m1[4], l1[4];
#pragma unroll
  for (int r = 0; r < 4; ++r) { m0[r] = m1[r] = -1e30f; l0[r] = l1[r] = 0.f; }
  int nt = (q0 + 47) >> 5;                            // 32-col tiles over [0, q0+16)

  const u16* kr0 = kbase + (size_t)l16 * 64 + quad * 8;
  bf16x8 nb00 = *(const bf16x8*)(kr0);
  bf16x8 nb01 = *(const bf16x8*)(kr0 + 32);
  bf16x8 nb10 = *(const bf16x8*)(kr0 + 1024);
  bf16x8 nb11 = *(const bf16x8*)(kr0 + 1024 + 32);
  for (int kt = 0; kt < nt; ++kt) {
    bf16x8 b00 = nb00, b01 = nb01, b10 = nb10, b11 = nb11;
    if (kt + 1 < nt) {
      const u16* kn = kbase + (size_t)((kt + 1) * 32 + l16) * 64 + quad * 8;
      nb00 = *(const bf16x8*)(kn);
      nb01 = *(const bf16x8*)(kn + 32);
      nb10 = *(const bf16x8*)(kn + 1024);
      nb11 = *(const bf16x8*)(kn + 1024 + 32);
    }
    f32x4 c0 = {0.f, 0.f, 0.f, 0.f}, c1 = c0;
    c0 = MFMA(aq0, b00, c0);
    c0 = MFMA(aq1, b01, c0);
    c1 = MFMA(aq0, b10, c1);
    c1 = MFMA(aq1, b11, c1);
    int col0 = kt * 32 + l16, col1 = col0 + 16;
#pragma unroll
    for (int r = 0; r < 4; ++r) {
      int q = q0 + quad * 4 + r;
      float v0 = (col0 <= q) ? c0[r] : -1e30f;        // chain 0
      float d0 = v0 - m0[r];
      float t0 = E2(-__builtin_fabsf(d0));
      bool g0 = d0 > 0.f;
      l0[r] = g0 ? __builtin_fmaf(l0[r], t0, 1.f) : (l0[r] + t0);
      m0[r] = g0 ? v0 : m0[r];
      float v1 = (col1 <= q) ? c1[r] : -1e30f;        // chain 1 (independent)
      float d1 = v1 - m1[r];
      float t1 = E2(-__builtin_fabsf(d1));
      bool g1 = d1 > 0.f;
      l1[r] = g1 ? __builtin_fmaf(l1[r], t1, 1.f) : (l1[r] + t1);
      m1[r] = g1 ? v1 : m1[r];
    }
  }
  float m[4], l[4];
#pragma unroll
  for (int r = 0; r < 4; ++r) {                       // merge the two chains
    float nm = fmaxf(m0[r], m1[r]);
    l[r] = l0[r] * E2(m0[r] - nm) + l1[r] * E2(m1[r] - nm);
    m[r] = nm;
  }
#pragma unroll
  for (int r = 0; r < 4; ++r) {                       // width-16 lane merge
#pragma unroll
    for (int off = 1; off < 16; off <<= 1) {
      float om = __shfl_xor(m[r], off, 16);
      float ol = __shfl_xor(l[r], off, 16);
      float nm = fmaxf(m[r], om);
      l[r] = l[r] * E2(m[r] - nm) + ol * E2(om - nm);
      m[r] = nm;
    }
  }
  float rl[4];
#pragma unroll
  for (int r = 0; r < 4; ++r) rl[r] = 1.f / l[r];

  // ---- pass 2 -------------------------------------------------------------
  f32x4 oacc[4];
#pragma unroll
  for (int s4 = 0; s4 < 4; ++s4) oacc[s4] = (f32x4){0.f, 0.f, 0.f, 0.f};
  float* pf = &Pf[w][0];
  const u16* vtb = Vt + (size_t)bh * 64 * 2048;
  float* wrow = Wout + (size_t)bh * 2048 * 2048;
  int srow = lane >> 3, scol = (lane & 7) << 2;       // coalesced store map

  int na = qmax / 32 + 1;                             // active 32-col tiles
  for (int kt2 = 0; kt2 < na; ++kt2) {
    int k0 = kt2 * 32;
    const u16* kr = kbase + (size_t)(k0 + l16) * 64 + quad * 8;
    bf16x8 b00 = *(const bf16x8*)(kr);
    bf16x8 b01 = *(const bf16x8*)(kr + 32);
    bf16x8 b10 = *(const bf16x8*)(kr + 1024);
    bf16x8 b11 = *(const bf16x8*)(kr + 1024 + 32);
    // V loads hoisted above the QK^T MFMAs — independent of cc, their ~200cy
    // L2 latency hides under the exp/staging phase.
    bf16x8 bv[4];
#pragma unroll
    for (int s4 = 0; s4 < 4; ++s4)
      bv[s4] = *(const bf16x8*)(vtb + (size_t)(s4 * 16 + l16) * 2048 + k0 + quad * 8);
    f32x4 cc[2] = {{0.f,0.f,0.f,0.f}, {0.f,0.f,0.f,0.f}};
    cc[0] = MFMA(aq0, b00, cc[0]);
    cc[0] = MFMA(aq1, b01, cc[0]);
    cc[1] = MFMA(aq0, b10, cc[1]);
    cc[1] = MFMA(aq1, b11, cc[1]);
#pragma unroll
    for (int sub = 0; sub < 2; ++sub) {
      int col = k0 + sub * 16 + l16;
#pragma unroll
      for (int r = 0; r < 4; ++r) {
        int q = q0 + quad * 4 + r;
        float p = (col <= q) ? E2(cc[sub][r] - m[r]) * rl[r] : 0.f;
        pf[(quad * 4 + r) * 36 + sub * 16 + l16] = p;
      }
    }
    // coalesced fp32 nt store: 2 float4/lane, 8 rows x 128B per instr;
    // non-temporal — Wout is write-once, never device-read, and allocating
    // 537 MB of streaming stores in L2 was evicting K/V.
    f32x4 v0 = *(const f32x4*)(pf + srow * 36 + scol);
    f32x4 v1 = *(const f32x4*)(pf + (srow + 8) * 36 + scol);
    __builtin_nontemporal_store(v0, (f32x4*)(wrow + (size_t)(q0 + srow) * 2048 + k0 + scol));
    __builtin_nontemporal_store(v1, (f32x4*)(wrow + (size_t)(q0 + srow + 8) * 2048 + k0 + scol));
    // PA fragment from fp32 staging; packed RNE cvt (4 instr for 8 elems)
    f32x4 pa0 = *(const f32x4*)(pf + l16 * 36 + quad * 8);
    f32x4 pa1 = *(const f32x4*)(pf + l16 * 36 + quad * 8 + 4);
    u32x4 pk;
    pk[0] = cvtpk_bf16(pa0[0], pa0[1]);
    pk[1] = cvtpk_bf16(pa0[2], pa0[3]);
    pk[2] = cvtpk_bf16(pa1[0], pa1[1]);
    pk[3] = cvtpk_bf16(pa1[2], pa1[3]);
    bf16x8 pa = __builtin_bit_cast(bf16x8, pk);
#pragma unroll
    for (int s4 = 0; s4 < 4; ++s4) {
      oacc[s4] = MFMA(pa, bv[s4], oacc[s4]);
    }
  }
  // zero-fill the masked remainder [na*32, 2048) — 1KB per instruction, nt
  int zstart = na * 32;
  f32x4 z = {0.f, 0.f, 0.f, 0.f};
  for (int r = 0; r < 16; ++r) {
    float* rb = wrow + (size_t)(q0 + r) * 2048;
    for (int c = zstart + (lane << 2); c < 2048; c += 256)
      __builtin_nontemporal_store(z, (f32x4*)(rb + c));
  }
  // ctx[b][s][h*64+d]
  int b = bh >> 4, h = bh & 15;
#pragma unroll
  for (int s4 = 0; s4 < 4; ++s4)
#pragma unroll
    for (int r = 0; r < 4; ++r) {
      int q = q0 + quad * 4 + r;
      int d = s4 * 16 + l16;
      ctx[((size_t)(b * 2048 + q)) * 1024 + h * 64 + d] = f2bf(oacc[s4][r]);
    }
}

// ---------------------------------------------------------------------------
extern "C" void kernel_launch(void* const* d_in, const int* in_sizes, int n_in,
                              void* d_out, int out_size, void* d_ws, size_t ws_size,
                              hipStream_t stream) {
  const float* hs     = (const float*)d_in[0];
  const float* w_attn = (const float*)d_in[1];
  const float* b_attn = (const float*)d_in[2];
  const float* w_proj = (const float*)d_in[3];
  const float* b_proj = (const float*)d_in[4];

  char*  outc  = (char*)d_out;
  float* out_f = (float*)d_out;
  float* Wout  = out_f + 4194304;                 // weights region (512 MB)

  // scratch carved out of d_out (dead/alive windows don't overlap):
  u16* qbuf = (u16*)outc;                         // attn_out region: Q (8 MB)
  u16* kbuf = (u16*)(outc + 8388608);             //                  K (8 MB)
  u16* hsb  = (u16*)(outc + 530579456);           // weights tail: hs bf16 (8 MB)
  u16* wtA  = (u16*)(outc + 538968064);           //               w_attn^T (6 MB)
  u16* vbuf = (u16*)(outc + 545259520);           //               V (8 MB)

  char* ws  = (char*)d_ws;                        // 18 MB of d_ws used
  u16*  vt  = (u16*)ws;                           // V^T (8 MB)
  u16*  ctx = (u16*)(ws + 8388608);               // pre-proj context (8 MB)
  u16*  wtP = (u16*)(ws + 16777216);              // w_proj^T (2 MB)

  k_cast<<<4096, 256, 0, stream>>>(hs, hsb, 4194304);
  k_transpose_cast<<<dim3(48, 16), 256, 0, stream>>>(w_attn, wtA, 1024, 3072);
  k_transpose_cast<<<dim3(16, 16), 256, 0, stream>>>(w_proj, wtP, 1024, 1024);
  k_gemm_qkv<<<dim3(24, 32), 256, 0, stream>>>(hsb, wtA, b_attn, qbuf, kbuf, vbuf);
  k_transpose_v<<<dim3(32, 32), 256, 0, stream>>>(vbuf, vt);
  k_attn<<<1024, 256, 0, stream>>>(qbuf, kbuf, vt, ctx, Wout);
  k_gemm_proj<<<dim3(16, 32), 256, 0, stream>>>(ctx, wtP, b_proj, out_f);
}

// Round 5
// 728.138 us; speedup vs baseline: 1.0542x; 1.0005x over previous
//
#include <hip/hip_runtime.h>

// ---------------------------------------------------------------------------
// TfmrAttention: B=2, S=2048, E=1024, H=16, D=64
// out = [attn_out (4,194,304 f32) | attn_weights (134,217,728 f32)]
// R3: k_attn load-balance (co-resident blocks carry constant causal work).
// R4: proj 128x64 (2 blk/CU); pass-1 single-exp update; pass-2 V hoist.
// R5: nt stores on Wout/proj (L2 hygiene for K/V); cvt_pk PA pack.  [732.6us]
// R6: REGRESSED (+35us, bundled reg-pressure changes) — reverted.
// R7: XCD-aware swizzle on both GEMMs.                              [728.5us]
// R8: pass-2 P staged across 4 K-tiles in LDS (Pf stride 36->132) so Wout
//     stores issue as 512B-contiguous runs per row instead of 128B — 4x the
//     payload per DRAM page visit on the 8KB-stride row pattern. Tile body
//     is unchanged R5 logic, #pragma unroll 1 (no R6-style pressure).
//     LDS 33.8KB/block: still 4 blocks/CU.
// ---------------------------------------------------------------------------

typedef unsigned short u16;
typedef __attribute__((ext_vector_type(8))) short bf16x8;   // 8 bf16 = 4 VGPRs
typedef __attribute__((ext_vector_type(4))) float f32x4;
typedef __attribute__((ext_vector_type(4))) unsigned short u16x4;
typedef __attribute__((ext_vector_type(4))) unsigned int u32x4;

#define MFMA(a, b, c) __builtin_amdgcn_mfma_f32_16x16x32_bf16((a), (b), (c), 0, 0, 0)

typedef const __attribute__((address_space(1))) void* gas_t;
typedef __attribute__((address_space(3))) void* las_t;
__device__ __forceinline__ void async_copy16(const void* g, void* l) {
  __builtin_amdgcn_global_load_lds((gas_t)g, (las_t)l, 16, 0, 0);
}

__device__ __forceinline__ u16 f2bf(float f) {          // RNE fp32->bf16
  unsigned u = __builtin_bit_cast(unsigned, f);
  u += 0x7FFFu + ((u >> 16) & 1u);
  return (u16)(u >> 16);
}
__device__ __forceinline__ float E2(float x) { return __builtin_amdgcn_exp2f(x); }
__device__ __forceinline__ unsigned cvtpk_bf16(float lo, float hi) {
  unsigned r;                                           // {lo16,hi16} RNE pack
  asm("v_cvt_pk_bf16_f32 %0, %1, %2" : "=v"(r) : "v"(lo), "v"(hi));
  return r;
}

// 0.125 * log2(e): fold 1/sqrt(64) and natural->base2 exp into Q
#define QSCALE 0.18033688011112042f

// ---- cast fp32 -> bf16, 4 elems/thread ------------------------------------
__global__ __launch_bounds__(256) void k_cast(const float* __restrict__ in,
                                              u16* __restrict__ out, int n) {
  int i = (blockIdx.x * 256 + threadIdx.x) * 4;
  if (i + 3 < n) {
    float4 v = *(const float4*)(in + i);
    u16x4 o = { f2bf(v.x), f2bf(v.y), f2bf(v.z), f2bf(v.w) };
    *(u16x4*)(out + i) = o;
  }
}

// ---- transpose + cast: W[Kd][Nd] fp32 -> Wt[Nd][Kd] bf16 -------------------
__global__ __launch_bounds__(256) void k_transpose_cast(const float* __restrict__ in,
                                                        u16* __restrict__ out,
                                                        int Kd, int Nd) {
  __shared__ float tile[64][65];
  int n0 = blockIdx.x * 64, k0 = blockIdx.y * 64;
  int t = threadIdx.x, col = t & 63, r4 = t >> 6;
#pragma unroll
  for (int ph = 0; ph < 16; ++ph) {
    int row = ph * 4 + r4;
    tile[row][col] = in[(size_t)(k0 + row) * Nd + n0 + col];
  }
  __syncthreads();
#pragma unroll
  for (int ph = 0; ph < 16; ++ph) {
    int row = ph * 4 + r4;
    out[(size_t)(n0 + row) * Kd + k0 + col] = f2bf(tile[col][row]);
  }
}

// ---- transpose bf16: V[bh][2048][64] -> Vt[bh][64][2048] -------------------
__global__ __launch_bounds__(256) void k_transpose_v(const u16* __restrict__ V,
                                                     u16* __restrict__ Vt) {
  __shared__ u16 tile[64][65];
  int bh = blockIdx.y, s0 = blockIdx.x * 64;
  int t = threadIdx.x, col = t & 63, r4 = t >> 6;
#pragma unroll
  for (int ph = 0; ph < 16; ++ph) {
    int row = ph * 4 + r4;
    tile[row][col] = V[((size_t)bh * 2048 + s0 + row) * 64 + col];
  }
  __syncthreads();
#pragma unroll
  for (int ph = 0; ph < 16; ++ph) {
    int row = ph * 4 + r4;
    Vt[((size_t)bh * 64 + row) * 2048 + s0 + col] = tile[col][row];
  }
}

// ---- m97-style GEMM core macro: 128x128 tile, BK=32, global_load_lds -------
// m0/n0 must be computed by the caller (allows XCD-aware swizzle).
#define GEMM_BODY()                                                            \
  __shared__ u16 As[128 * 32];                                                 \
  __shared__ u16 Bs[128 * 32];                                                 \
  int t = threadIdx.x;                                                         \
  int wave = t >> 6, lane = t & 63, quad = lane >> 4, l16 = lane & 15;         \
  int wm = wave >> 1, wn = wave & 1;                                           \
  int f1 = wave * 64 + lane, f2 = f1 + 256;                                    \
  const u16* gA1 = A + (size_t)(m0 + (f1 >> 2)) * 1024 + (f1 & 3) * 8;         \
  const u16* gA2 = A + (size_t)(m0 + (f2 >> 2)) * 1024 + (f2 & 3) * 8;         \
  const u16* gB1 = Bt + (size_t)(n0 + (f1 >> 2)) * 1024 + (f1 & 3) * 8;        \
  const u16* gB2 = Bt + (size_t)(n0 + (f2 >> 2)) * 1024 + (f2 & 3) * 8;        \
  u16* lA1 = As + wave * 512;                                                  \
  u16* lA2 = As + 2048 + wave * 512;                                           \
  u16* lB1 = Bs + wave * 512;                                                  \
  u16* lB2 = Bs + 2048 + wave * 512;                                           \
  f32x4 acc[4][4];                                                             \
  for (int i = 0; i < 4; ++i)                                                  \
    for (int j = 0; j < 4; ++j) acc[i][j] = (f32x4){0.f, 0.f, 0.f, 0.f};       \
  for (int k0 = 0; k0 < 1024; k0 += 32) {                                      \
    async_copy16(gA1 + k0, lA1);                                               \
    async_copy16(gA2 + k0, lA2);                                               \
    async_copy16(gB1 + k0, lB1);                                               \
    async_copy16(gB2 + k0, lB2);                                               \
    __syncthreads();                                                           \
    bf16x8 fa[4], fb[4];                                                       \
    _Pragma("unroll") for (int i = 0; i < 4; ++i)                              \
        fa[i] = *(const bf16x8*)(As + (wm * 64 + i * 16 + l16) * 32 + quad * 8);\
    _Pragma("unroll") for (int j = 0; j < 4; ++j)                              \
        fb[j] = *(const bf16x8*)(Bs + (wn * 64 + j * 16 + l16) * 32 + quad * 8);\
    _Pragma("unroll") for (int i = 0; i < 4; ++i)                              \
      _Pragma("unroll") for (int j = 0; j < 4; ++j)                            \
          acc[i][j] = MFMA(fa[i], fb[j], acc[i][j]);                           \
    __syncthreads();                                                           \
  }

// GEMM1: hs[4096][1024] @ W[1024][3072] (+b) -> Q,K,V bf16 [b,h,s,d]
// XCD swizzle: each XCD owns 4 contiguous m-rows x 24 n-tiles; the 1MB
// A-chunk stays L2-resident while n walks fastest.
__global__ __launch_bounds__(256) void k_gemm_qkv(const u16* __restrict__ A,
                                                  const u16* __restrict__ Bt,
                                                  const float* __restrict__ bias,
                                                  u16* __restrict__ Q,
                                                  u16* __restrict__ Kp,
                                                  u16* __restrict__ V) {
  int lid = blockIdx.y * 24 + blockIdx.x;             // 768 = 8 * 96
  int wg = (lid & 7) * 96 + (lid >> 3);
  int m0 = (wg / 24) * 128, n0 = (wg % 24) * 128;
  GEMM_BODY()
#pragma unroll
  for (int j = 0; j < 4; ++j) {
    int n = n0 + wn * 64 + j * 16 + l16;
    float bv = bias[n];
    int which = n >> 10, e = n & 1023, h = e >> 6, d = e & 63;
#pragma unroll
    for (int i = 0; i < 4; ++i)
#pragma unroll
      for (int r = 0; r < 4; ++r) {
        int m = m0 + wm * 64 + i * 16 + quad * 4 + r;
        int b = m >> 11, s = m & 2047;
        float v = acc[i][j][r] + bv;
        size_t off = ((size_t)((b * 16 + h) * 2048 + s)) * 64 + d;
        if (which == 0)      Q[off]  = f2bf(v * QSCALE);
        else if (which == 1) Kp[off] = f2bf(v);
        else                 V[off]  = f2bf(v);
      }
  }
}

// GEMM2: ctx[4096][1024] @ Wp[1024][1024] (+b) -> out fp32
// 128(M)x64(N) tile -> 512 blocks = 2 blocks/CU; nt stores; XCD swizzle.
__global__ __launch_bounds__(256) void k_gemm_proj(const u16* __restrict__ A,
                                                   const u16* __restrict__ Bt,
                                                   const float* __restrict__ bias,
                                                   float* __restrict__ out) {
  __shared__ u16 As[128 * 32];
  __shared__ u16 Bs[64 * 32];
  int t = threadIdx.x;
  int wave = t >> 6, lane = t & 63, quad = lane >> 4, l16 = lane & 15;
  int wm = wave >> 1, wn = wave & 1;
  int lid = blockIdx.y * 16 + blockIdx.x;             // 512 = 8 * 64
  int wg = (lid & 7) * 64 + (lid >> 3);
  int m0 = (wg >> 4) * 128, n0 = (wg & 15) * 64;
  int f1 = wave * 64 + lane, f2 = f1 + 256;
  const u16* gA1 = A + (size_t)(m0 + (f1 >> 2)) * 1024 + (f1 & 3) * 8;
  const u16* gA2 = A + (size_t)(m0 + (f2 >> 2)) * 1024 + (f2 & 3) * 8;
  const u16* gB1 = Bt + (size_t)(n0 + (f1 >> 2)) * 1024 + (f1 & 3) * 8;
  u16* lA1 = As + wave * 512;
  u16* lA2 = As + 2048 + wave * 512;
  u16* lB1 = Bs + wave * 512;
  f32x4 acc[4][2];
  for (int i = 0; i < 4; ++i)
    for (int j = 0; j < 2; ++j) acc[i][j] = (f32x4){0.f, 0.f, 0.f, 0.f};
  for (int k0 = 0; k0 < 1024; k0 += 32) {
    async_copy16(gA1 + k0, lA1);
    async_copy16(gA2 + k0, lA2);
    async_copy16(gB1 + k0, lB1);
    __syncthreads();
    bf16x8 fa[4], fb[2];
#pragma unroll
    for (int i = 0; i < 4; ++i)
      fa[i] = *(const bf16x8*)(As + (wm * 64 + i * 16 + l16) * 32 + quad * 8);
#pragma unroll
    for (int j = 0; j < 2; ++j)
      fb[j] = *(const bf16x8*)(Bs + (wn * 32 + j * 16 + l16) * 32 + quad * 8);
#pragma unroll
    for (int i = 0; i < 4; ++i)
#pragma unroll
      for (int j = 0; j < 2; ++j) acc[i][j] = MFMA(fa[i], fb[j], acc[i][j]);
    __syncthreads();
  }
#pragma unroll
  for (int j = 0; j < 2; ++j) {
    int n = n0 + wn * 32 + j * 16 + l16;
    float bv = bias[n];
#pragma unroll
    for (int i = 0; i < 4; ++i)
#pragma unroll
      for (int r = 0; r < 4; ++r) {
        int m = m0 + wm * 64 + i * 16 + quad * 4 + r;
        __builtin_nontemporal_store(acc[i][j][r] + bv, &out[(size_t)m * 1024 + n]);
      }
  }
}

// ---- fused causal attention ------------------------------------------------
// Grid: 1024 1-D blocks. bh = id&31, i = id>>5 -> (j = i&7, s = i>>3);
// q-tile qt = {j, 15-j, 16+j, 31-j}[s]. Co-resident blocks on a CU are ids
// ≡ c (mod 256) => same j, all four s => Σqt = 62 = constant per-CU work;
// per-XCD blocks share only 4 distinct bh => K/V working set 2MB fits L2.
__global__ __launch_bounds__(256, 4) void k_attn(const u16* __restrict__ Q,
                                                 const u16* __restrict__ Kp,
                                                 const u16* __restrict__ Vt,
                                                 u16* __restrict__ ctx,
                                                 float* __restrict__ Wout) {
  __shared__ float Pf[4][16 * 132];                   // fp32 P panel, 4 tiles
  int t = threadIdx.x;
  int w = t >> 6, lane = t & 63, quad = lane >> 4, l16 = lane & 15;
  int id = blockIdx.x;
  int bh = id & 31;
  int ii = id >> 5, jj = ii & 7, ss = ii >> 3;
  int qt = (ss == 0) ? jj : (ss == 1) ? 15 - jj : (ss == 2) ? 16 + jj : 31 - jj;
  int q0 = qt * 64 + w * 16;

  const u16* qrow = Q + ((size_t)bh * 2048 + q0 + l16) * 64 + quad * 8;
  bf16x8 aq0 = *(const bf16x8*)(qrow);
  bf16x8 aq1 = *(const bf16x8*)(qrow + 32);

  const u16* kbase = Kp + (size_t)bh * 2048 * 64;
  int qmax = q0 + 15;

  // ---- pass 1: dual-chain online softmax over 32-col tiles, K prefetch ----
  // single-exp update: t = exp2(-|d|), d=v-m:  d>0 ? l=fma(l,t,1),m=v : l+=t.
  // Masked lanes (v=m=-1e30 -> d=0 -> l+=1) keep m=-1e30, die at lane-merge.
  float m0[4], l0[4], m1[4], l1[4];
#pragma unroll
  for (int r = 0; r < 4; ++r) { m0[r] = m1[r] = -1e30f; l0[r] = l1[r] = 0.f; }
  int nt = (q0 + 47) >> 5;                            // 32-col tiles over [0, q0+16)

  const u16* kr0 = kbase + (size_t)l16 * 64 + quad * 8;
  bf16x8 nb00 = *(const bf16x8*)(kr0);
  bf16x8 nb01 = *(const bf16x8*)(kr0 + 32);
  bf16x8 nb10 = *(const bf16x8*)(kr0 + 1024);
  bf16x8 nb11 = *(const bf16x8*)(kr0 + 1024 + 32);
  for (int kt = 0; kt < nt; ++kt) {
    bf16x8 b00 = nb00, b01 = nb01, b10 = nb10, b11 = nb11;
    if (kt + 1 < nt) {
      const u16* kn = kbase + (size_t)((kt + 1) * 32 + l16) * 64 + quad * 8;
      nb00 = *(const bf16x8*)(kn);
      nb01 = *(const bf16x8*)(kn + 32);
      nb10 = *(const bf16x8*)(kn + 1024);
      nb11 = *(const bf16x8*)(kn + 1024 + 32);
    }
    f32x4 c0 = {0.f, 0.f, 0.f, 0.f}, c1 = c0;
    c0 = MFMA(aq0, b00, c0);
    c0 = MFMA(aq1, b01, c0);
    c1 = MFMA(aq0, b10, c1);
    c1 = MFMA(aq1, b11, c1);
    int col0 = kt * 32 + l16, col1 = col0 + 16;
#pragma unroll
    for (int r = 0; r < 4; ++r) {
      int q = q0 + quad * 4 + r;
      float v0 = (col0 <= q) ? c0[r] : -1e30f;        // chain 0
      float d0 = v0 - m0[r];
      float t0 = E2(-__builtin_fabsf(d0));
      bool g0 = d0 > 0.f;
      l0[r] = g0 ? __builtin_fmaf(l0[r], t0, 1.f) : (l0[r] + t0);
      m0[r] = g0 ? v0 : m0[r];
      float v1 = (col1 <= q) ? c1[r] : -1e30f;        // chain 1 (independent)
      float d1 = v1 - m1[r];
      float t1 = E2(-__builtin_fabsf(d1));
      bool g1 = d1 > 0.f;
      l1[r] = g1 ? __builtin_fmaf(l1[r], t1, 1.f) : (l1[r] + t1);
      m1[r] = g1 ? v1 : m1[r];
    }
  }
  float m[4], l[4];
#pragma unroll
  for (int r = 0; r < 4; ++r) {                       // merge the two chains
    float nm = fmaxf(m0[r], m1[r]);
    l[r] = l0[r] * E2(m0[r] - nm) + l1[r] * E2(m1[r] - nm);
    m[r] = nm;
  }
#pragma unroll
  for (int r = 0; r < 4; ++r) {                       // width-16 lane merge
#pragma unroll
    for (int off = 1; off < 16; off <<= 1) {
      float om = __shfl_xor(m[r], off, 16);
      float ol = __shfl_xor(l[r], off, 16);
      float nm = fmaxf(m[r], om);
      l[r] = l[r] * E2(m[r] - nm) + ol * E2(om - nm);
      m[r] = nm;
    }
  }
  float rl[4];
#pragma unroll
  for (int r = 0; r < 4; ++r) rl[r] = 1.f / l[r];

  // ---- pass 2: groups of 4 K-tiles; P panel in LDS; 512B-run stores -------
  f32x4 oacc[4];
#pragma unroll
  for (int s4 = 0; s4 < 4; ++s4) oacc[s4] = (f32x4){0.f, 0.f, 0.f, 0.f};
  float* pf = &Pf[w][0];
  const u16* vtb = Vt + (size_t)bh * 64 * 2048;
  float* wrow = Wout + (size_t)bh * 2048 * 2048;
  int srow = lane >> 3, scol = (lane & 7) << 2;       // 128B tail-store map
  int row2 = lane >> 5, col2 = (lane & 31) << 2;      // 512B group-store map

  int na = qmax / 32 + 1;                             // active 32-col tiles
  int nfull = na & ~3;                                // 4-tile groups
  for (int g = 0; g < nfull; g += 4) {
#pragma unroll 1
    for (int kt2 = g; kt2 < g + 4; ++kt2) {
      int k0 = kt2 * 32;
      int co = k0 & 96;                               // col offset in panel
      const u16* kr = kbase + (size_t)(k0 + l16) * 64 + quad * 8;
      bf16x8 b00 = *(const bf16x8*)(kr);
      bf16x8 b01 = *(const bf16x8*)(kr + 32);
      bf16x8 b10 = *(const bf16x8*)(kr + 1024);
      bf16x8 b11 = *(const bf16x8*)(kr + 1024 + 32);
      bf16x8 bv[4];
#pragma unroll
      for (int s4 = 0; s4 < 4; ++s4)
        bv[s4] = *(const bf16x8*)(vtb + (size_t)(s4 * 16 + l16) * 2048 + k0 + quad * 8);
      f32x4 cc[2] = {{0.f,0.f,0.f,0.f}, {0.f,0.f,0.f,0.f}};
      cc[0] = MFMA(aq0, b00, cc[0]);
      cc[0] = MFMA(aq1, b01, cc[0]);
      cc[1] = MFMA(aq0, b10, cc[1]);
      cc[1] = MFMA(aq1, b11, cc[1]);
#pragma unroll
      for (int sub = 0; sub < 2; ++sub) {
        int col = k0 + sub * 16 + l16;
#pragma unroll
        for (int r = 0; r < 4; ++r) {
          int q = q0 + quad * 4 + r;
          float p = (col <= q) ? E2(cc[sub][r] - m[r]) * rl[r] : 0.f;
          pf[(quad * 4 + r) * 132 + co + sub * 16 + l16] = p;
        }
      }
      f32x4 pa0 = *(const f32x4*)(pf + l16 * 132 + co + quad * 8);
      f32x4 pa1 = *(const f32x4*)(pf + l16 * 132 + co + quad * 8 + 4);
      u32x4 pk;
      pk[0] = cvtpk_bf16(pa0[0], pa0[1]);
      pk[1] = cvtpk_bf16(pa0[2], pa0[3]);
      pk[2] = cvtpk_bf16(pa1[0], pa1[1]);
      pk[3] = cvtpk_bf16(pa1[2], pa1[3]);
      bf16x8 pa = __builtin_bit_cast(bf16x8, pk);
#pragma unroll
      for (int s4 = 0; s4 < 4; ++s4) {
        oacc[s4] = MFMA(pa, bv[s4], oacc[s4]);
      }
    }
    // 16 rows x 512B contiguous: 2 rows per instr (lanes 0-31 / 32-63)
#pragma unroll
    for (int rr = 0; rr < 8; ++rr) {
      int row = rr * 2 + row2;
      f32x4 vv = *(const f32x4*)(pf + row * 132 + col2);
      __builtin_nontemporal_store(
          vv, (f32x4*)(wrow + (size_t)(q0 + row) * 2048 + g * 32 + col2));
    }
  }
  // tail tiles (na % 4): original per-tile 128B path
#pragma unroll 1
  for (int kt2 = nfull; kt2 < na; ++kt2) {
    int k0 = kt2 * 32;
    const u16* kr = kbase + (size_t)(k0 + l16) * 64 + quad * 8;
    bf16x8 b00 = *(const bf16x8*)(kr);
    bf16x8 b01 = *(const bf16x8*)(kr + 32);
    bf16x8 b10 = *(const bf16x8*)(kr + 1024);
    bf16x8 b11 = *(const bf16x8*)(kr + 1024 + 32);
    bf16x8 bv[4];
#pragma unroll
    for (int s4 = 0; s4 < 4; ++s4)
      bv[s4] = *(const bf16x8*)(vtb + (size_t)(s4 * 16 + l16) * 2048 + k0 + quad * 8);
    f32x4 cc[2] = {{0.f,0.f,0.f,0.f}, {0.f,0.f,0.f,0.f}};
    cc[0] = MFMA(aq0, b00, cc[0]);
    cc[0] = MFMA(aq1, b01, cc[0]);
    cc[1] = MFMA(aq0, b10, cc[1]);
    cc[1] = MFMA(aq1, b11, cc[1]);
#pragma unroll
    for (int sub = 0; sub < 2; ++sub) {
      int col = k0 + sub * 16 + l16;
#pragma unroll
      for (int r = 0; r < 4; ++r) {
        int q = q0 + quad * 4 + r;
        float p = (col <= q) ? E2(cc[sub][r] - m[r]) * rl[r] : 0.f;
        pf[(quad * 4 + r) * 132 + sub * 16 + l16] = p;
      }
    }
    f32x4 v0 = *(const f32x4*)(pf + srow * 132 + scol);
    f32x4 v1 = *(const f32x4*)(pf + (srow + 8) * 132 + scol);
    __builtin_nontemporal_store(v0, (f32x4*)(wrow + (size_t)(q0 + srow) * 2048 + k0 + scol));
    __builtin_nontemporal_store(v1, (f32x4*)(wrow + (size_t)(q0 + srow + 8) * 2048 + k0 + scol));
    f32x4 pa0 = *(const f32x4*)(pf + l16 * 132 + quad * 8);
    f32x4 pa1 = *(const f32x4*)(pf + l16 * 132 + quad * 8 + 4);
    u32x4 pk;
    pk[0] = cvtpk_bf16(pa0[0], pa0[1]);
    pk[1] = cvtpk_bf16(pa0[2], pa0[3]);
    pk[2] = cvtpk_bf16(pa1[0], pa1[1]);
    pk[3] = cvtpk_bf16(pa1[2], pa1[3]);
    bf16x8 pa = __builtin_bit_cast(bf16x8, pk);
#pragma unroll
    for (int s4 = 0; s4 < 4; ++s4) {
      oacc[s4] = MFMA(pa, bv[s4], oacc[s4]);
    }
  }
  // zero-fill the masked remainder [na*32, 2048) — 1KB per instruction, nt
  int zstart = na * 32;
  f32x4 z = {0.f, 0.f, 0.f, 0.f};
  for (int r = 0; r < 16; ++r) {
    float* rb = wrow + (size_t)(q0 + r) * 2048;
    for (int c = zstart + (lane << 2); c < 2048; c += 256)
      __builtin_nontemporal_store(z, (f32x4*)(rb + c));
  }
  // ctx[b][s][h*64+d]
  int b = bh >> 4, h = bh & 15;
#pragma unroll
  for (int s4 = 0; s4 < 4; ++s4)
#pragma unroll
    for (int r = 0; r < 4; ++r) {
      int q = q0 + quad * 4 + r;
      int d = s4 * 16 + l16;
      ctx[((size_t)(b * 2048 + q)) * 1024 + h * 64 + d] = f2bf(oacc[s4][r]);
    }
}

// ---------------------------------------------------------------------------
extern "C" void kernel_launch(void* const* d_in, const int* in_sizes, int n_in,
                              void* d_out, int out_size, void* d_ws, size_t ws_size,
                              hipStream_t stream) {
  const float* hs     = (const float*)d_in[0];
  const float* w_attn = (const float*)d_in[1];
  const float* b_attn = (const float*)d_in[2];
  const float* w_proj = (const float*)d_in[3];
  const float* b_proj = (const float*)d_in[4];

  char*  outc  = (char*)d_out;
  float* out_f = (float*)d_out;
  float* Wout  = out_f + 4194304;                 // weights region (512 MB)

  // scratch carved out of d_out (dead/alive windows don't overlap):
  u16* qbuf = (u16*)outc;                         // attn_out region: Q (8 MB)
  u16* kbuf = (u16*)(outc + 8388608);             //                  K (8 MB)
  u16* hsb  = (u16*)(outc + 530579456);           // weights tail: hs bf16 (8 MB)
  u16* wtA  = (u16*)(outc + 538968064);           //               w_attn^T (6 MB)
  u16* vbuf = (u16*)(outc + 545259520);           //               V (8 MB)

  char* ws  = (char*)d_ws;                        // 18 MB of d_ws used
  u16*  vt  = (u16*)ws;                           // V^T (8 MB)
  u16*  ctx = (u16*)(ws + 8388608);               // pre-proj context (8 MB)
  u16*  wtP = (u16*)(ws + 16777216);              // w_proj^T (2 MB)

  k_cast<<<4096, 256, 0, stream>>>(hs, hsb, 4194304);
  k_transpose_cast<<<dim3(48, 16), 256, 0, stream>>>(w_attn, wtA, 1024, 3072);
  k_transpose_cast<<<dim3(16, 16), 256, 0, stream>>>(w_proj, wtP, 1024, 1024);
  k_gemm_qkv<<<dim3(24, 32), 256, 0, stream>>>(hsb, wtA, b_attn, qbuf, kbuf, vbuf);
  k_transpose_v<<<dim3(32, 32), 256, 0, stream>>>(vbuf, vt);
  k_attn<<<1024, 256, 0, stream>>>(qbuf, kbuf, vt, ctx, Wout);
  k_gemm_proj<<<dim3(16, 32), 256, 0, stream>>>(ctx, wtP, b_proj, out_f);
}

// Round 7
// 727.686 us; speedup vs baseline: 1.0549x; 1.0006x over previous
//
#include <hip/hip_runtime.h>

// ---------------------------------------------------------------------------
// TfmrAttention: B=2, S=2048, E=1024, H=16, D=64
// out = [attn_out (4,194,304 f32) | attn_weights (134,217,728 f32)]
// R3: k_attn load-balance (co-resident blocks carry constant causal work).
// R4: proj 128x64 (2 blk/CU); pass-1 single-exp update; pass-2 V hoist.
// R5: nt stores on Wout/proj (L2 hygiene for K/V); cvt_pk PA pack.  [732.6us]
// R6: REGRESSED (+35us, bundled: K-dbuf + zero-fill-at-start + setprio).
// R7: XCD-aware swizzle on both GEMMs.                              [728.5us]
// R8: P panel in LDS, 512B-run stores — NULL (store granularity not the
//     binding constraint).                                          [728.1us]
// R9: isolate R6's change #1: pass-2 K register prefetch, SPLIT issue
//     (2 loads right after QK MFMAs free the current-K regs, 2 after the
//     P/LDS phase) to keep peak VGPR < 128. Nothing else touched.
//     Discriminates {R6 = spills} vs {R6 = zero-fill write burst}.
// R10: resubmit of R9 — round 6 bench was an infra failure (container
//     acquisition), no measurement was taken.
// ---------------------------------------------------------------------------

typedef unsigned short u16;
typedef __attribute__((ext_vector_type(8))) short bf16x8;   // 8 bf16 = 4 VGPRs
typedef __attribute__((ext_vector_type(4))) float f32x4;
typedef __attribute__((ext_vector_type(4))) unsigned short u16x4;
typedef __attribute__((ext_vector_type(4))) unsigned int u32x4;

#define MFMA(a, b, c) __builtin_amdgcn_mfma_f32_16x16x32_bf16((a), (b), (c), 0, 0, 0)

typedef const __attribute__((address_space(1))) void* gas_t;
typedef __attribute__((address_space(3))) void* las_t;
__device__ __forceinline__ void async_copy16(const void* g, void* l) {
  __builtin_amdgcn_global_load_lds((gas_t)g, (las_t)l, 16, 0, 0);
}

__device__ __forceinline__ u16 f2bf(float f) {          // RNE fp32->bf16
  unsigned u = __builtin_bit_cast(unsigned, f);
  u += 0x7FFFu + ((u >> 16) & 1u);
  return (u16)(u >> 16);
}
__device__ __forceinline__ float E2(float x) { return __builtin_amdgcn_exp2f(x); }
__device__ __forceinline__ unsigned cvtpk_bf16(float lo, float hi) {
  unsigned r;                                           // {lo16,hi16} RNE pack
  asm("v_cvt_pk_bf16_f32 %0, %1, %2" : "=v"(r) : "v"(lo), "v"(hi));
  return r;
}

// 0.125 * log2(e): fold 1/sqrt(64) and natural->base2 exp into Q
#define QSCALE 0.18033688011112042f

// ---- cast fp32 -> bf16, 4 elems/thread ------------------------------------
__global__ __launch_bounds__(256) void k_cast(const float* __restrict__ in,
                                              u16* __restrict__ out, int n) {
  int i = (blockIdx.x * 256 + threadIdx.x) * 4;
  if (i + 3 < n) {
    float4 v = *(const float4*)(in + i);
    u16x4 o = { f2bf(v.x), f2bf(v.y), f2bf(v.z), f2bf(v.w) };
    *(u16x4*)(out + i) = o;
  }
}

// ---- transpose + cast: W[Kd][Nd] fp32 -> Wt[Nd][Kd] bf16 -------------------
__global__ __launch_bounds__(256) void k_transpose_cast(const float* __restrict__ in,
                                                        u16* __restrict__ out,
                                                        int Kd, int Nd) {
  __shared__ float tile[64][65];
  int n0 = blockIdx.x * 64, k0 = blockIdx.y * 64;
  int t = threadIdx.x, col = t & 63, r4 = t >> 6;
#pragma unroll
  for (int ph = 0; ph < 16; ++ph) {
    int row = ph * 4 + r4;
    tile[row][col] = in[(size_t)(k0 + row) * Nd + n0 + col];
  }
  __syncthreads();
#pragma unroll
  for (int ph = 0; ph < 16; ++ph) {
    int row = ph * 4 + r4;
    out[(size_t)(n0 + row) * Kd + k0 + col] = f2bf(tile[col][row]);
  }
}

// ---- transpose bf16: V[bh][2048][64] -> Vt[bh][64][2048] -------------------
__global__ __launch_bounds__(256) void k_transpose_v(const u16* __restrict__ V,
                                                     u16* __restrict__ Vt) {
  __shared__ u16 tile[64][65];
  int bh = blockIdx.y, s0 = blockIdx.x * 64;
  int t = threadIdx.x, col = t & 63, r4 = t >> 6;
#pragma unroll
  for (int ph = 0; ph < 16; ++ph) {
    int row = ph * 4 + r4;
    tile[row][col] = V[((size_t)bh * 2048 + s0 + row) * 64 + col];
  }
  __syncthreads();
#pragma unroll
  for (int ph = 0; ph < 16; ++ph) {
    int row = ph * 4 + r4;
    Vt[((size_t)bh * 64 + row) * 2048 + s0 + col] = tile[col][row];
  }
}

// ---- m97-style GEMM core macro: 128x128 tile, BK=32, global_load_lds -------
// m0/n0 must be computed by the caller (allows XCD-aware swizzle).
#define GEMM_BODY()                                                            \
  __shared__ u16 As[128 * 32];                                                 \
  __shared__ u16 Bs[128 * 32];                                                 \
  int t = threadIdx.x;                                                         \
  int wave = t >> 6, lane = t & 63, quad = lane >> 4, l16 = lane & 15;         \
  int wm = wave >> 1, wn = wave & 1;                                           \
  int f1 = wave * 64 + lane, f2 = f1 + 256;                                    \
  const u16* gA1 = A + (size_t)(m0 + (f1 >> 2)) * 1024 + (f1 & 3) * 8;         \
  const u16* gA2 = A + (size_t)(m0 + (f2 >> 2)) * 1024 + (f2 & 3) * 8;         \
  const u16* gB1 = Bt + (size_t)(n0 + (f1 >> 2)) * 1024 + (f1 & 3) * 8;        \
  const u16* gB2 = Bt + (size_t)(n0 + (f2 >> 2)) * 1024 + (f2 & 3) * 8;        \
  u16* lA1 = As + wave * 512;                                                  \
  u16* lA2 = As + 2048 + wave * 512;                                           \
  u16* lB1 = Bs + wave * 512;                                                  \
  u16* lB2 = Bs + 2048 + wave * 512;                                           \
  f32x4 acc[4][4];                                                             \
  for (int i = 0; i < 4; ++i)                                                  \
    for (int j = 0; j < 4; ++j) acc[i][j] = (f32x4){0.f, 0.f, 0.f, 0.f};       \
  for (int k0 = 0; k0 < 1024; k0 += 32) {                                      \
    async_copy16(gA1 + k0, lA1);                                               \
    async_copy16(gA2 + k0, lA2);                                               \
    async_copy16(gB1 + k0, lB1);                                               \
    async_copy16(gB2 + k0, lB2);                                               \
    __syncthreads();                                                           \
    bf16x8 fa[4], fb[4];                                                       \
    _Pragma("unroll") for (int i = 0; i < 4; ++i)                              \
        fa[i] = *(const bf16x8*)(As + (wm * 64 + i * 16 + l16) * 32 + quad * 8);\
    _Pragma("unroll") for (int j = 0; j < 4; ++j)                              \
        fb[j] = *(const bf16x8*)(Bs + (wn * 64 + j * 16 + l16) * 32 + quad * 8);\
    _Pragma("unroll") for (int i = 0; i < 4; ++i)                              \
      _Pragma("unroll") for (int j = 0; j < 4; ++j)                            \
          acc[i][j] = MFMA(fa[i], fb[j], acc[i][j]);                           \
    __syncthreads();                                                           \
  }

// GEMM1: hs[4096][1024] @ W[1024][3072] (+b) -> Q,K,V bf16 [b,h,s,d]
// XCD swizzle: each XCD owns 4 contiguous m-rows x 24 n-tiles; the 1MB
// A-chunk stays L2-resident while n walks fastest.
__global__ __launch_bounds__(256) void k_gemm_qkv(const u16* __restrict__ A,
                                                  const u16* __restrict__ Bt,
                                                  const float* __restrict__ bias,
                                                  u16* __restrict__ Q,
                                                  u16* __restrict__ Kp,
                                                  u16* __restrict__ V) {
  int lid = blockIdx.y * 24 + blockIdx.x;             // 768 = 8 * 96
  int wg = (lid & 7) * 96 + (lid >> 3);
  int m0 = (wg / 24) * 128, n0 = (wg % 24) * 128;
  GEMM_BODY()
#pragma unroll
  for (int j = 0; j < 4; ++j) {
    int n = n0 + wn * 64 + j * 16 + l16;
    float bv = bias[n];
    int which = n >> 10, e = n & 1023, h = e >> 6, d = e & 63;
#pragma unroll
    for (int i = 0; i < 4; ++i)
#pragma unroll
      for (int r = 0; r < 4; ++r) {
        int m = m0 + wm * 64 + i * 16 + quad * 4 + r;
        int b = m >> 11, s = m & 2047;
        float v = acc[i][j][r] + bv;
        size_t off = ((size_t)((b * 16 + h) * 2048 + s)) * 64 + d;
        if (which == 0)      Q[off]  = f2bf(v * QSCALE);
        else if (which == 1) Kp[off] = f2bf(v);
        else                 V[off]  = f2bf(v);
      }
  }
}

// GEMM2: ctx[4096][1024] @ Wp[1024][1024] (+b) -> out fp32
// 128(M)x64(N) tile -> 512 blocks = 2 blocks/CU; nt stores; XCD swizzle.
__global__ __launch_bounds__(256) void k_gemm_proj(const u16* __restrict__ A,
                                                   const u16* __restrict__ Bt,
                                                   const float* __restrict__ bias,
                                                   float* __restrict__ out) {
  __shared__ u16 As[128 * 32];
  __shared__ u16 Bs[64 * 32];
  int t = threadIdx.x;
  int wave = t >> 6, lane = t & 63, quad = lane >> 4, l16 = lane & 15;
  int wm = wave >> 1, wn = wave & 1;
  int lid = blockIdx.y * 16 + blockIdx.x;             // 512 = 8 * 64
  int wg = (lid & 7) * 64 + (lid >> 3);
  int m0 = (wg >> 4) * 128, n0 = (wg & 15) * 64;
  int f1 = wave * 64 + lane, f2 = f1 + 256;
  const u16* gA1 = A + (size_t)(m0 + (f1 >> 2)) * 1024 + (f1 & 3) * 8;
  const u16* gA2 = A + (size_t)(m0 + (f2 >> 2)) * 1024 + (f2 & 3) * 8;
  const u16* gB1 = Bt + (size_t)(n0 + (f1 >> 2)) * 1024 + (f1 & 3) * 8;
  u16* lA1 = As + wave * 512;
  u16* lA2 = As + 2048 + wave * 512;
  u16* lB1 = Bs + wave * 512;
  f32x4 acc[4][2];
  for (int i = 0; i < 4; ++i)
    for (int j = 0; j < 2; ++j) acc[i][j] = (f32x4){0.f, 0.f, 0.f, 0.f};
  for (int k0 = 0; k0 < 1024; k0 += 32) {
    async_copy16(gA1 + k0, lA1);
    async_copy16(gA2 + k0, lA2);
    async_copy16(gB1 + k0, lB1);
    __syncthreads();
    bf16x8 fa[4], fb[2];
#pragma unroll
    for (int i = 0; i < 4; ++i)
      fa[i] = *(const bf16x8*)(As + (wm * 64 + i * 16 + l16) * 32 + quad * 8);
#pragma unroll
    for (int j = 0; j < 2; ++j)
      fb[j] = *(const bf16x8*)(Bs + (wn * 32 + j * 16 + l16) * 32 + quad * 8);
#pragma unroll
    for (int i = 0; i < 4; ++i)
#pragma unroll
      for (int j = 0; j < 2; ++j) acc[i][j] = MFMA(fa[i], fb[j], acc[i][j]);
    __syncthreads();
  }
#pragma unroll
  for (int j = 0; j < 2; ++j) {
    int n = n0 + wn * 32 + j * 16 + l16;
    float bv = bias[n];
#pragma unroll
    for (int i = 0; i < 4; ++i)
#pragma unroll
      for (int r = 0; r < 4; ++r) {
        int m = m0 + wm * 64 + i * 16 + quad * 4 + r;
        __builtin_nontemporal_store(acc[i][j][r] + bv, &out[(size_t)m * 1024 + n]);
      }
  }
}

// ---- fused causal attention ------------------------------------------------
// Grid: 1024 1-D blocks. bh = id&31, i = id>>5 -> (j = i&7, s = i>>3);
// q-tile qt = {j, 15-j, 16+j, 31-j}[s]. Co-resident blocks on a CU are ids
// ≡ c (mod 256) => same j, all four s => Σqt = 62 = constant per-CU work;
// per-XCD blocks share only 4 distinct bh => K/V working set 2MB fits L2.
__global__ __launch_bounds__(256, 4) void k_attn(const u16* __restrict__ Q,
                                                 const u16* __restrict__ Kp,
                                                 const u16* __restrict__ Vt,
                                                 u16* __restrict__ ctx,
                                                 float* __restrict__ Wout) {
  __shared__ float Pf[4][16 * 132];                   // fp32 P panel, 4 tiles
  int t = threadIdx.x;
  int w = t >> 6, lane = t & 63, quad = lane >> 4, l16 = lane & 15;
  int id = blockIdx.x;
  int bh = id & 31;
  int ii = id >> 5, jj = ii & 7, ss = ii >> 3;
  int qt = (ss == 0) ? jj : (ss == 1) ? 15 - jj : (ss == 2) ? 16 + jj : 31 - jj;
  int q0 = qt * 64 + w * 16;

  const u16* qrow = Q + ((size_t)bh * 2048 + q0 + l16) * 64 + quad * 8;
  bf16x8 aq0 = *(const bf16x8*)(qrow);
  bf16x8 aq1 = *(const bf16x8*)(qrow + 32);

  const u16* kbase = Kp + (size_t)bh * 2048 * 64;
  int qmax = q0 + 15;

  // ---- pass 1: dual-chain online softmax over 32-col tiles, K prefetch ----
  // single-exp update: t = exp2(-|d|), d=v-m:  d>0 ? l=fma(l,t,1),m=v : l+=t.
  // Masked lanes (v=m=-1e30 -> d=0 -> l+=1) keep m=-1e30, die at lane-merge.
  float m0[4], l0[4], m1[4], l1[4];
#pragma unroll
  for (int r = 0; r < 4; ++r) { m0[r] = m1[r] = -1e30f; l0[r] = l1[r] = 0.f; }
  int nt = (q0 + 47) >> 5;                            // 32-col tiles over [0, q0+16)

  const u16* kr0 = kbase + (size_t)l16 * 64 + quad * 8;
  bf16x8 nb00 = *(const bf16x8*)(kr0);
  bf16x8 nb01 = *(const bf16x8*)(kr0 + 32);
  bf16x8 nb10 = *(const bf16x8*)(kr0 + 1024);
  bf16x8 nb11 = *(const bf16x8*)(kr0 + 1024 + 32);
  for (int kt = 0; kt < nt; ++kt) {
    bf16x8 b00 = nb00, b01 = nb01, b10 = nb10, b11 = nb11;
    if (kt + 1 < nt) {
      const u16* kn = kbase + (size_t)((kt + 1) * 32 + l16) * 64 + quad * 8;
      nb00 = *(const bf16x8*)(kn);
      nb01 = *(const bf16x8*)(kn + 32);
      nb10 = *(const bf16x8*)(kn + 1024);
      nb11 = *(const bf16x8*)(kn + 1024 + 32);
    }
    f32x4 c0 = {0.f, 0.f, 0.f, 0.f}, c1 = c0;
    c0 = MFMA(aq0, b00, c0);
    c0 = MFMA(aq1, b01, c0);
    c1 = MFMA(aq0, b10, c1);
    c1 = MFMA(aq1, b11, c1);
    int col0 = kt * 32 + l16, col1 = col0 + 16;
#pragma unroll
    for (int r = 0; r < 4; ++r) {
      int q = q0 + quad * 4 + r;
      float v0 = (col0 <= q) ? c0[r] : -1e30f;        // chain 0
      float d0 = v0 - m0[r];
      float t0 = E2(-__builtin_fabsf(d0));
      bool g0 = d0 > 0.f;
      l0[r] = g0 ? __builtin_fmaf(l0[r], t0, 1.f) : (l0[r] + t0);
      m0[r] = g0 ? v0 : m0[r];
      float v1 = (col1 <= q) ? c1[r] : -1e30f;        // chain 1 (independent)
      float d1 = v1 - m1[r];
      float t1 = E2(-__builtin_fabsf(d1));
      bool g1 = d1 > 0.f;
      l1[r] = g1 ? __builtin_fmaf(l1[r], t1, 1.f) : (l1[r] + t1);
      m1[r] = g1 ? v1 : m1[r];
    }
  }
  float m[4], l[4];
#pragma unroll
  for (int r = 0; r < 4; ++r) {                       // merge the two chains
    float nm = fmaxf(m0[r], m1[r]);
    l[r] = l0[r] * E2(m0[r] - nm) + l1[r] * E2(m1[r] - nm);
    m[r] = nm;
  }
#pragma unroll
  for (int r = 0; r < 4; ++r) {                       // width-16 lane merge
#pragma unroll
    for (int off = 1; off < 16; off <<= 1) {
      float om = __shfl_xor(m[r], off, 16);
      float ol = __shfl_xor(l[r], off, 16);
      float nm = fmaxf(m[r], om);
      l[r] = l[r] * E2(m[r] - nm) + ol * E2(om - nm);
      m[r] = nm;
    }
  }
  float rl[4];
#pragma unroll
  for (int r = 0; r < 4; ++r) rl[r] = 1.f / l[r];

  // ---- pass 2: groups of 4 K-tiles; P panel in LDS; 512B-run stores;
  //      R9: K register prefetch, split issue --------------------------------
  f32x4 oacc[4];
#pragma unroll
  for (int s4 = 0; s4 < 4; ++s4) oacc[s4] = (f32x4){0.f, 0.f, 0.f, 0.f};
  float* pf = &Pf[w][0];
  const u16* vtb = Vt + (size_t)bh * 64 * 2048;
  float* wrow = Wout + (size_t)bh * 2048 * 2048;
  int srow = lane >> 3, scol = (lane & 7) << 2;       // 128B tail-store map
  int row2 = lane >> 5, col2 = (lane & 31) << 2;      // 512B group-store map

  int na = qmax / 32 + 1;                             // active 32-col tiles
  int nfull = na & ~3;                                // 4-tile groups

  // K(0) preload — kb regs carried across all of pass 2
  bf16x8 kb00, kb01, kb10, kb11;
  {
    const u16* kr = kbase + (size_t)l16 * 64 + quad * 8;
    kb00 = *(const bf16x8*)(kr);
    kb01 = *(const bf16x8*)(kr + 32);
    kb10 = *(const bf16x8*)(kr + 1024);
    kb11 = *(const bf16x8*)(kr + 1024 + 32);
  }

  for (int g = 0; g < nfull; g += 4) {
#pragma unroll 1
    for (int kt2 = g; kt2 < g + 4; ++kt2) {
      int k0 = kt2 * 32;
      int co = k0 & 96;                               // col offset in panel
      bf16x8 b00 = kb00, b01 = kb01, b10 = kb10, b11 = kb11;
      bf16x8 bv[4];
#pragma unroll
      for (int s4 = 0; s4 < 4; ++s4)
        bv[s4] = *(const bf16x8*)(vtb + (size_t)(s4 * 16 + l16) * 2048 + k0 + quad * 8);
      f32x4 cc[2] = {{0.f,0.f,0.f,0.f}, {0.f,0.f,0.f,0.f}};
      cc[0] = MFMA(aq0, b00, cc[0]);
      cc[0] = MFMA(aq1, b01, cc[0]);
      cc[1] = MFMA(aq0, b10, cc[1]);
      cc[1] = MFMA(aq1, b11, cc[1]);
      // prefetch K(t+1), first half — current-K regs are dead after the MFMAs
      bool more = (kt2 + 1 < na);
      const u16* kn = kbase + (size_t)((kt2 + 1) * 32 + l16) * 64 + quad * 8;
      if (more) {
        kb00 = *(const bf16x8*)(kn);
        kb01 = *(const bf16x8*)(kn + 32);
      }
#pragma unroll
      for (int sub = 0; sub < 2; ++sub) {
        int col = k0 + sub * 16 + l16;
#pragma unroll
        for (int r = 0; r < 4; ++r) {
          int q = q0 + quad * 4 + r;
          float p = (col <= q) ? E2(cc[sub][r] - m[r]) * rl[r] : 0.f;
          pf[(quad * 4 + r) * 132 + co + sub * 16 + l16] = p;
        }
      }
      // prefetch K(t+1), second half
      if (more) {
        kb10 = *(const bf16x8*)(kn + 1024);
        kb11 = *(const bf16x8*)(kn + 1024 + 32);
      }
      f32x4 pa0 = *(const f32x4*)(pf + l16 * 132 + co + quad * 8);
      f32x4 pa1 = *(const f32x4*)(pf + l16 * 132 + co + quad * 8 + 4);
      u32x4 pk;
      pk[0] = cvtpk_bf16(pa0[0], pa0[1]);
      pk[1] = cvtpk_bf16(pa0[2], pa0[3]);
      pk[2] = cvtpk_bf16(pa1[0], pa1[1]);
      pk[3] = cvtpk_bf16(pa1[2], pa1[3]);
      bf16x8 pa = __builtin_bit_cast(bf16x8, pk);
#pragma unroll
      for (int s4 = 0; s4 < 4; ++s4) {
        oacc[s4] = MFMA(pa, bv[s4], oacc[s4]);
      }
    }
    // 16 rows x 512B contiguous: 2 rows per instr (lanes 0-31 / 32-63)
#pragma unroll
    for (int rr = 0; rr < 8; ++rr) {
      int row = rr * 2 + row2;
      f32x4 vv = *(const f32x4*)(pf + row * 132 + col2);
      __builtin_nontemporal_store(
          vv, (f32x4*)(wrow + (size_t)(q0 + row) * 2048 + g * 32 + col2));
    }
  }
  // tail tiles (na % 4): per-tile 128B path, same kb prefetch chain
#pragma unroll 1
  for (int kt2 = nfull; kt2 < na; ++kt2) {
    int k0 = kt2 * 32;
    bf16x8 b00 = kb00, b01 = kb01, b10 = kb10, b11 = kb11;
    bf16x8 bv[4];
#pragma unroll
    for (int s4 = 0; s4 < 4; ++s4)
      bv[s4] = *(const bf16x8*)(vtb + (size_t)(s4 * 16 + l16) * 2048 + k0 + quad * 8);
    f32x4 cc[2] = {{0.f,0.f,0.f,0.f}, {0.f,0.f,0.f,0.f}};
    cc[0] = MFMA(aq0, b00, cc[0]);
    cc[0] = MFMA(aq1, b01, cc[0]);
    cc[1] = MFMA(aq0, b10, cc[1]);
    cc[1] = MFMA(aq1, b11, cc[1]);
    bool more = (kt2 + 1 < na);
    const u16* kn = kbase + (size_t)((kt2 + 1) * 32 + l16) * 64 + quad * 8;
    if (more) {
      kb00 = *(const bf16x8*)(kn);
      kb01 = *(const bf16x8*)(kn + 32);
      kb10 = *(const bf16x8*)(kn + 1024);
      kb11 = *(const bf16x8*)(kn + 1024 + 32);
    }
#pragma unroll
    for (int sub = 0; sub < 2; ++sub) {
      int col = k0 + sub * 16 + l16;
#pragma unroll
      for (int r = 0; r < 4; ++r) {
        int q = q0 + quad * 4 + r;
        float p = (col <= q) ? E2(cc[sub][r] - m[r]) * rl[r] : 0.f;
        pf[(quad * 4 + r) * 132 + sub * 16 + l16] = p;
      }
    }
    f32x4 v0 = *(const f32x4*)(pf + srow * 132 + scol);
    f32x4 v1 = *(const f32x4*)(pf + (srow + 8) * 132 + scol);
    __builtin_nontemporal_store(v0, (f32x4*)(wrow + (size_t)(q0 + srow) * 2048 + k0 + scol));
    __builtin_nontemporal_store(v1, (f32x4*)(wrow + (size_t)(q0 + srow + 8) * 2048 + k0 + scol));
    f32x4 pa0 = *(const f32x4*)(pf + l16 * 132 + quad * 8);
    f32x4 pa1 = *(const f32x4*)(pf + l16 * 132 + quad * 8 + 4);
    u32x4 pk;
    pk[0] = cvtpk_bf16(pa0[0], pa0[1]);
    pk[1] = cvtpk_bf16(pa0[2], pa0[3]);
    pk[2] = cvtpk_bf16(pa1[0], pa1[1]);
    pk[3] = cvtpk_bf16(pa1[2], pa1[3]);
    bf16x8 pa = __builtin_bit_cast(bf16x8, pk);
#pragma unroll
    for (int s4 = 0; s4 < 4; ++s4) {
      oacc[s4] = MFMA(pa, bv[s4], oacc[s4]);
    }
  }
  // zero-fill the masked remainder [na*32, 2048) — 1KB per instruction, nt
  int zstart = na * 32;
  f32x4 z = {0.f, 0.f, 0.f, 0.f};
  for (int r = 0; r < 16; ++r) {
    float* rb = wrow + (size_t)(q0 + r) * 2048;
    for (int c = zstart + (lane << 2); c < 2048; c += 256)
      __builtin_nontemporal_store(z, (f32x4*)(rb + c));
  }
  // ctx[b][s][h*64+d]
  int b = bh >> 4, h = bh & 15;
#pragma unroll
  for (int s4 = 0; s4 < 4; ++s4)
#pragma unroll
    for (int r = 0; r < 4; ++r) {
      int q = q0 + quad * 4 + r;
      int d = s4 * 16 + l16;
      ctx[((size_t)(b * 2048 + q)) * 1024 + h * 64 + d] = f2bf(oacc[s4][r]);
    }
}

// ---------------------------------------------------------------------------
extern "C" void kernel_launch(void* const* d_in, const int* in_sizes, int n_in,
                              void* d_out, int out_size, void* d_ws, size_t ws_size,
                              hipStream_t stream) {
  const float* hs     = (const float*)d_in[0];
  const float* w_attn = (const float*)d_in[1];
  const float* b_attn = (const float*)d_in[2];
  const float* w_proj = (const float*)d_in[3];
  const float* b_proj = (const float*)d_in[4];

  char*  outc  = (char*)d_out;
  float* out_f = (float*)d_out;
  float* Wout  = out_f + 4194304;                 // weights region (512 MB)

  // scratch carved out of d_out (dead/alive windows don't overlap):
  u16* qbuf = (u16*)outc;                         // attn_out region: Q (8 MB)
  u16* kbuf = (u16*)(outc + 8388608);             //                  K (8 MB)
  u16* hsb  = (u16*)(outc + 530579456);           // weights tail: hs bf16 (8 MB)
  u16* wtA  = (u16*)(outc + 538968064);           //               w_attn^T (6 MB)
  u16* vbuf = (u16*)(outc + 545259520);           //               V (8 MB)

  char* ws  = (char*)d_ws;                        // 18 MB of d_ws used
  u16*  vt  = (u16*)ws;                           // V^T (8 MB)
  u16*  ctx = (u16*)(ws + 8388608);               // pre-proj context (8 MB)
  u16*  wtP = (u16*)(ws + 16777216);              // w_proj^T (2 MB)

  k_cast<<<4096, 256, 0, stream>>>(hs, hsb, 4194304);
  k_transpose_cast<<<dim3(48, 16), 256, 0, stream>>>(w_attn, wtA, 1024, 3072);
  k_transpose_cast<<<dim3(16, 16), 256, 0, stream>>>(w_proj, wtP, 1024, 1024);
  k_gemm_qkv<<<dim3(24, 32), 256, 0, stream>>>(hsb, wtA, b_attn, qbuf, kbuf, vbuf);
  k_transpose_v<<<dim3(32, 32), 256, 0, stream>>>(vbuf, vt);
  k_attn<<<1024, 256, 0, stream>>>(qbuf, kbuf, vt, ctx, Wout);
  k_gemm_proj<<<dim3(16, 32), 256, 0, stream>>>(ctx, wtP, b_proj, out_f);
}